// Round 5
// baseline (224.986 us; speedup 1.0000x reference)
//
#include <hip/hip_runtime.h>
#include <math.h>

#define Bn 8
#define CIN 64
#define HH 32
#define WW 32
#define HW 1024
#define CQKV 192
#define NHh 4
#define DKHd 16
#define DVHd 16

typedef _Float16 half4_t __attribute__((ext_vector_type(4)));
typedef _Float16 half8_t __attribute__((ext_vector_type(8)));
typedef float f32x4 __attribute__((ext_vector_type(4)));

// ---------------------------------------------------------------------------
// Prep A: x (f32, [sb][ci][32][32]) -> xt (f16, [sb][34][34][64]) zero-padded.
// ---------------------------------------------------------------------------
__global__ __launch_bounds__(256) void prep_xt_kernel(
    const float* __restrict__ x1, const float* __restrict__ x2,
    const float* __restrict__ x12, _Float16* __restrict__ xt)
{
    const int sb = blockIdx.x;           // s*8 + b
    const int s  = sb >> 3, b = sb & 7;
    const int ci0 = blockIdx.y * 8;
    const float* x = (s == 0) ? x1 : (s == 1) ? x2 : x12;
    const float* xb = x + (size_t)b * CIN * HW;

    for (int pos = threadIdx.x; pos < 34 * 34; pos += 256) {
        const int row = pos / 34, col = pos % 34;
        const int gy = row - 1, gx = col - 1;
        half8_t v;
        if ((unsigned)gy < 32u && (unsigned)gx < 32u) {
            #pragma unroll
            for (int j = 0; j < 8; ++j)
                v[j] = (_Float16)xb[(size_t)(ci0 + j) * HW + gy * 32 + gx];
        } else {
            #pragma unroll
            for (int j = 0; j < 8; ++j) v[j] = (_Float16)0.f;
        }
        *reinterpret_cast<half8_t*>(&xt[((size_t)sb * 1156 + pos) * 64 + ci0]) = v;
    }
}

// ---------------------------------------------------------------------------
// Prep B: weights -> A-fragment layout wf[s][ct(12)][ks(36)][lane(64)][4] f16,
// with 0.25 q-scale folded in (co<64).
// ---------------------------------------------------------------------------
__global__ __launch_bounds__(256) void prep_wf_kernel(
    const float* __restrict__ w1, const float* __restrict__ w2,
    const float* __restrict__ w12, _Float16* __restrict__ wf)
{
    const int f = blockIdx.x * 256 + threadIdx.x;   // 82944 frags
    if (f >= 3 * 12 * 36 * 64) return;
    const int lane = f & 63;
    int r = f >> 6;
    const int ks = r % 36; r /= 36;
    const int ct = r % 12; const int s = r / 12;
    const float* w = (s == 0) ? w1 : (s == 1) ? w2 : w12;

    const int tap = ks >> 2;
    const int ci_b = (ks & 3) * 16 + (lane >> 4) * 4;
    const int co = ct * 16 + (lane & 15);
    const float scale = (co < 64) ? 0.25f : 1.f;

    half4_t v;
    #pragma unroll
    for (int j = 0; j < 4; ++j)
        v[j] = (_Float16)(w[((size_t)co * 64 + ci_b + j) * 9 + tap] * scale);
    *reinterpret_cast<half4_t*>(&wf[(size_t)f * 4]) = v;
}

// ---------------------------------------------------------------------------
// Kernel 1: implicit-GEMM 3x3 conv via MFMA (unchanged from round 3).
// ---------------------------------------------------------------------------
__global__ __launch_bounds__(256) void conv_mfma_kernel(
    const _Float16* __restrict__ xt, const _Float16* __restrict__ wf,
    const float* __restrict__ b1, const float* __restrict__ b2,
    const float* __restrict__ b12, float* __restrict__ qkv)
{
    __shared__ _Float16 xs[8704];        // 4*34*64
    const int strip = blockIdx.x;
    const int b = blockIdx.y, s = blockIdx.z;
    const int sb = s * Bn + b;
    const int tid = threadIdx.x;
    const int w = tid >> 6, lane = tid & 63, g = lane >> 4, lq = lane & 15;
    const int y0 = strip * 2;

    const half4_t* src = reinterpret_cast<const half4_t*>(
        xt + ((size_t)sb * 1156 + y0 * 34) * 64);
    for (int c = tid; c < 2176; c += 256) {
        const int cic = c & 15;
        const int colrow = c >> 4;
        const int xx = colrow % 34;
        const int lofs = colrow * 64 + ((cic ^ (xx & 15)) << 2);
        *reinterpret_cast<half4_t*>(&xs[lofs]) = src[c];
    }
    __syncthreads();

    f32x4 acc[3][4];
    #pragma unroll
    for (int cc = 0; cc < 3; ++cc)
        #pragma unroll
        for (int t = 0; t < 4; ++t) acc[cc][t] = (f32x4){0.f, 0.f, 0.f, 0.f};

    const _Float16* wfs = wf + ((size_t)(s * 12 + w * 3) * 36) * 256;

    #pragma unroll
    for (int tap = 0; tap < 9; ++tap) {
        const int ky = tap / 3, kx = tap % 3;
        #pragma unroll
        for (int sub = 0; sub < 4; ++sub) {
            const int ks = tap * 4 + sub;
            half4_t af[3];
            #pragma unroll
            for (int cc = 0; cc < 3; ++cc)
                af[cc] = *reinterpret_cast<const half4_t*>(
                    &wfs[((size_t)cc * 36 + ks) * 256 + lane * 4]);
            half4_t bf[4];
            #pragma unroll
            for (int t = 0; t < 4; ++t) {
                const int ry = (t >> 1) + ky;
                const int xx = (t & 1) * 16 + lq + kx;
                const int cichunk = sub * 4 + g;
                bf[t] = *reinterpret_cast<const half4_t*>(
                    &xs[(ry * 34 + xx) * 64 + ((cichunk ^ (xx & 15)) << 2)]);
            }
            #pragma unroll
            for (int cc = 0; cc < 3; ++cc)
                #pragma unroll
                for (int t = 0; t < 4; ++t)
                    acc[cc][t] = __builtin_amdgcn_mfma_f32_16x16x16f16(
                        af[cc], bf[t], acc[cc][t], 0, 0, 0);
        }
    }

    const float* bi = (s == 0) ? b1 : (s == 1) ? b2 : b12;
    float* outb = qkv + (size_t)sb * CQKV * HW;
    #pragma unroll
    for (int cc = 0; cc < 3; ++cc) {
        const int ct = w * 3 + cc;
        const float bsc = (ct < 4) ? 0.25f : 1.f;
        const f32x4 bv4 = *reinterpret_cast<const f32x4*>(&bi[ct * 16 + g * 4]);
        #pragma unroll
        for (int t = 0; t < 4; ++t) {
            const int px = strip * 64 + t * 16 + lq;
            #pragma unroll
            for (int r = 0; r < 4; ++r) {
                const int ch = ct * 16 + g * 4 + r;
                outb[(size_t)ch * HW + px] = acc[cc][t][r] + bsc * bv4[r];
            }
        }
    }
}

// ---------------------------------------------------------------------------
// Kernel 2: rel-logit precompute (unchanged).
// ---------------------------------------------------------------------------
__global__ __launch_bounds__(256) void qrel_kernel(
    const float* __restrict__ qkv,
    const float* __restrict__ relw, const float* __restrict__ relh,
    float* __restrict__ qrw, float* __restrict__ qrh)
{
    const int m  = blockIdx.x;          // 0..62
    const int bh = blockIdx.y;          // b*4+h
    const int b  = bh >> 2, h = bh & 3;

    float ww[16], wh[16];
    #pragma unroll
    for (int d = 0; d < 16; ++d) {
        ww[d] = relw[m * 16 + d];
        wh[d] = relh[m * 16 + d];
    }
    const float* qb = qkv + ((size_t)b * CQKV + h * 16) * HW;
    for (int i = threadIdx.x; i < HW; i += 256) {
        float sw = 0.f, sh = 0.f;
        #pragma unroll
        for (int d = 0; d < 16; ++d) {
            const float qv = qb[(size_t)d * HW + i];
            sw = fmaf(qv, ww[d], sw);
            sh = fmaf(qv, wh[d], sh);
        }
        qrw[((size_t)bh * 64 + m) * HW + i] = sw;
        qrh[((size_t)bh * 64 + m) * HW + i] = sh;
    }
}

// ---------------------------------------------------------------------------
// Kernel 3: MFMA flash attention — TWO-PASS softmax (round 4).
// Pass 1: scores via mfma, per-lane running max only (no shfl/exp/rescale in
// the loop; chunks independent -> pipelined). One cross-lane reduce total.
// Pass 2: recompute scores, p = exp(s - M) <= 1, accumulate PV + lsum.
// qrh values cached in 32 VGPRs up front (fully-unrolled loops, static idx).
// ---------------------------------------------------------------------------
__global__ __launch_bounds__(256, 2) void attn_mfma_kernel(
    const float* __restrict__ qkv,
    const float* __restrict__ qrw, const float* __restrict__ qrh,
    float* __restrict__ o)
{
    __shared__ _Float16 kf_lds[16384];   // 32 KB: K fragments
    __shared__ _Float16 vf_lds[16384];   // 32 KB: V fragments

    const int S   = blockIdx.z;
    const int bh  = blockIdx.y;
    const int b   = bh >> 2, hd = bh & 3;
    const int tid = threadIdx.x;
    const int w    = tid >> 6;
    const int lane = tid & 63;
    const int g    = lane >> 4;
    const int lq   = lane & 15;
    const size_t SS = (size_t)Bn * CQKV * HW;

    const float* qsrc = qkv + S * SS + ((size_t)b * CQKV + hd * 16) * HW;
    const float* vsrc = qkv + S * SS + ((size_t)b * CQKV + 128 + hd * 16) * HW;
    const float* k1p;
    const float* k2p;
    if (S == 2) {
        k1p = qkv + 0 * SS + ((size_t)b * CQKV + 64 + hd * 16) * HW;
        k2p = qkv + 1 * SS + ((size_t)b * CQKV + 64 + hd * 16) * HW;
    } else {
        k1p = qkv + 2 * SS + ((size_t)b * CQKV + 64 + hd * 16) * HW;
        k2p = k1p;
    }

    // ---- stage K,V as MFMA fragments (f32 global -> f16 LDS) -------------
    #pragma unroll 4
    for (int it = 0; it < 16; ++it) {
        const int idx = it * 256 + tid;
        const int kt  = idx >> 6, l = idx & 63;
        const int row = l & 15;
        const int d0  = (l >> 4) * 4;
        const int lofs = (kt >> 1) * 512 + l * 8 + (kt & 1) * 4;

        const int key = kt * 16 + row;
        half4_t kh;
        #pragma unroll
        for (int j = 0; j < 4; ++j) {
            float x = k1p[(size_t)(d0 + j) * HW + key];
            if (S == 2) x -= k2p[(size_t)(d0 + j) * HW + key];
            kh[j] = (_Float16)x;
        }
        *reinterpret_cast<half4_t*>(&kf_lds[lofs]) = kh;

        const f32x4 vv = *reinterpret_cast<const f32x4*>(
            &vsrc[(size_t)row * HW + kt * 16 + d0]);
        half4_t vh;
        #pragma unroll
        for (int j = 0; j < 4; ++j) vh[j] = (_Float16)vv[j];
        *reinterpret_cast<half4_t*>(&vf_lds[lofs]) = vh;
    }

    // ---- per-wave Q fragment + rel caches (all in regs, static idx) ------
    const int qb0 = blockIdx.x * 64 + w * 16;
    const int i   = qb0 + lq;
    const int x1  = i & 31, y1 = i >> 5;

    half4_t qf;
    #pragma unroll
    for (int j = 0; j < 4; ++j)
        qf[j] = (_Float16)qsrc[(size_t)(g * 4 + j) * HW + i];

    float rwc0[4], rwc1[4], qrhc[32];
    if (S == 0) {
        #pragma unroll
        for (int r = 0; r < 4; ++r) {
            rwc0[r] = qrw[((size_t)bh * 64 + (g * 4 + r      - x1 + 31)) * HW + i];
            rwc1[r] = qrw[((size_t)bh * 64 + (g * 4 + r + 16 - x1 + 31)) * HW + i];
        }
        #pragma unroll
        for (int c = 0; c < 32; ++c)
            qrhc[c] = qrh[((size_t)bh * 64 + (c - y1 + 31)) * HW + i];
    }

    __syncthreads();

    const f32x4 zero4 = {0.f, 0.f, 0.f, 0.f};

    // ---- pass 1: global max (no cross-lane ops in loop) -------------------
    float vmax = -1e30f;
    #pragma unroll
    for (int c = 0; c < 32; ++c) {
        const half8_t kk = *reinterpret_cast<const half8_t*>(&kf_lds[c * 512 + lane * 8]);
        const half4_t ka = __builtin_shufflevector(kk, kk, 0, 1, 2, 3);
        const half4_t kb = __builtin_shufflevector(kk, kk, 4, 5, 6, 7);
        f32x4 s0 = __builtin_amdgcn_mfma_f32_16x16x16f16(ka, qf, zero4, 0, 0, 0);
        f32x4 s1 = __builtin_amdgcn_mfma_f32_16x16x16f16(kb, qf, zero4, 0, 0, 0);
        if (S == 0) {
            const float rh = qrhc[c];
            #pragma unroll
            for (int r = 0; r < 4; ++r) {
                s0[r] += rh + rwc0[r];
                s1[r] += rh + rwc1[r];
            }
        }
        const float m01 = fmaxf(fmaxf(s0[0], s0[1]), fmaxf(s0[2], s0[3]));
        const float m23 = fmaxf(fmaxf(s1[0], s1[1]), fmaxf(s1[2], s1[3]));
        vmax = fmaxf(vmax, fmaxf(m01, m23));
    }
    vmax = fmaxf(vmax, __shfl_xor(vmax, 16));
    vmax = fmaxf(vmax, __shfl_xor(vmax, 32));
    const float M = vmax;

    // ---- pass 2: exp + PV accumulate --------------------------------------
    float lsum = 0.f;
    f32x4 acc = {0.f, 0.f, 0.f, 0.f};
    #pragma unroll
    for (int c = 0; c < 32; ++c) {
        const half8_t kk = *reinterpret_cast<const half8_t*>(&kf_lds[c * 512 + lane * 8]);
        const half8_t vv = *reinterpret_cast<const half8_t*>(&vf_lds[c * 512 + lane * 8]);
        const half4_t ka = __builtin_shufflevector(kk, kk, 0, 1, 2, 3);
        const half4_t kb = __builtin_shufflevector(kk, kk, 4, 5, 6, 7);
        f32x4 s0 = __builtin_amdgcn_mfma_f32_16x16x16f16(ka, qf, zero4, 0, 0, 0);
        f32x4 s1 = __builtin_amdgcn_mfma_f32_16x16x16f16(kb, qf, zero4, 0, 0, 0);
        if (S == 0) {
            const float rh = qrhc[c];
            #pragma unroll
            for (int r = 0; r < 4; ++r) {
                s0[r] += rh + rwc0[r];
                s1[r] += rh + rwc1[r];
            }
        }
        half4_t pa, pb;
        #pragma unroll
        for (int r = 0; r < 4; ++r) {
            const float p0 = __expf(s0[r] - M);
            const float p1 = __expf(s1[r] - M);
            lsum += p0 + p1;
            pa[r] = (_Float16)p0;
            pb[r] = (_Float16)p1;
        }
        const half4_t va = __builtin_shufflevector(vv, vv, 0, 1, 2, 3);
        const half4_t vb = __builtin_shufflevector(vv, vv, 4, 5, 6, 7);
        acc = __builtin_amdgcn_mfma_f32_16x16x16f16(va, pa, acc, 0, 0, 0);
        acc = __builtin_amdgcn_mfma_f32_16x16x16f16(vb, pb, acc, 0, 0, 0);
    }

    lsum += __shfl_xor(lsum, 16);
    lsum += __shfl_xor(lsum, 32);
    const float inv = 1.f / lsum;

    float* op = o + ((((size_t)S * Bn + b) * NHh + hd) * HW) * 16;
    f32x4 res;
    #pragma unroll
    for (int r = 0; r < 4; ++r) res[r] = acc[r] * inv;
    *reinterpret_cast<f32x4*>(&op[(size_t)i * 16 + g * 4]) = res;
}

// ---------------------------------------------------------------------------
// Kernel 4: 1x1 output conv (unchanged).
// ---------------------------------------------------------------------------
__global__ __launch_bounds__(256) void out_conv_kernel(
    const float* __restrict__ o, const float* __restrict__ wout,
    const float* __restrict__ bout, float* __restrict__ out)
{
    const int co = blockIdx.x;
    const int sb = blockIdx.y;
    const int tid = threadIdx.x;
    const float* ob = o + (size_t)sb * 64 * HW;

    float acc[4] = {0.f, 0.f, 0.f, 0.f};
    for (int c = 0; c < 64; ++c) {
        const float wv = wout[co * 64 + c];
        #pragma unroll
        for (int p = 0; p < 4; ++p)
            acc[p] = fmaf(wv, ob[(size_t)c * HW + tid + p * 256], acc[p]);
    }
    const float bv = bout[co];
    #pragma unroll
    for (int p = 0; p < 4; ++p)
        out[((size_t)sb * 64 + co) * HW + tid + p * 256] = acc[p] + bv;
}

// ---------------------------------------------------------------------------
extern "C" void kernel_launch(void* const* d_in, const int* in_sizes, int n_in,
                              void* d_out, int out_size, void* d_ws, size_t ws_size,
                              hipStream_t stream)
{
    const float* x1   = (const float*)d_in[0];
    const float* x2   = (const float*)d_in[1];
    const float* x12  = (const float*)d_in[2];
    const float* wq1  = (const float*)d_in[3];
    const float* bq1  = (const float*)d_in[4];
    const float* wq2  = (const float*)d_in[5];
    const float* bq2  = (const float*)d_in[6];
    const float* wq12 = (const float*)d_in[7];
    const float* bq12 = (const float*)d_in[8];
    const float* wout = (const float*)d_in[9];
    const float* bout = (const float*)d_in[10];
    const float* relw = (const float*)d_in[11];
    const float* relh = (const float*)d_in[12];

    float* ws  = (float*)d_ws;
    float* qkv = ws;                                   // 3*8*192*1024
    float* qrw = qkv + (size_t)3 * Bn * CQKV * HW;     // 32*64*1024
    float* qrh = qrw + (size_t)32 * 64 * HW;
    float* o   = qrh + (size_t)32 * 64 * HW;           // 3*8*4*1024*16

    _Float16* xt = (_Float16*)qrw;                     // aliases (dead before qrel)
    _Float16* wf = (_Float16*)qrh;

    prep_xt_kernel<<<dim3(24, 8), 256, 0, stream>>>(x1, x2, x12, xt);
    prep_wf_kernel<<<dim3(324), 256, 0, stream>>>(wq1, wq2, wq12, wf);

    conv_mfma_kernel<<<dim3(16, 8, 3), 256, 0, stream>>>(
        xt, wf, bq1, bq2, bq12, qkv);

    qrel_kernel<<<dim3(63, 32), 256, 0, stream>>>(qkv, relw, relh, qrw, qrh);

    attn_mfma_kernel<<<dim3(16, 32, 3), 256, 0, stream>>>(qkv, qrw, qrh, o);

    out_conv_kernel<<<dim3(64, 24), 256, 0, stream>>>(o, wout, bout, (float*)d_out);
}

// Round 6
// 105.429 us; speedup vs baseline: 2.1340x; 2.1340x over previous
//
#include <hip/hip_runtime.h>
#include <math.h>

#define Bn 8
#define CIN 64
#define HH 32
#define WW 32
#define HW 1024
#define CQKV 192
#define NHh 4
#define DKHd 16
#define DVHd 16

typedef _Float16 half4_t __attribute__((ext_vector_type(4)));
typedef _Float16 half8_t __attribute__((ext_vector_type(8)));
typedef float f32x4 __attribute__((ext_vector_type(4)));

// ---------------------------------------------------------------------------
// Prep A: x (f32, [sb][ci][32][32]) -> xt (f16, [sb][34][34][64]) zero-padded.
// ---------------------------------------------------------------------------
__global__ __launch_bounds__(256) void prep_xt_kernel(
    const float* __restrict__ x1, const float* __restrict__ x2,
    const float* __restrict__ x12, _Float16* __restrict__ xt)
{
    const int sb = blockIdx.x;           // s*8 + b
    const int s  = sb >> 3, b = sb & 7;
    const int ci0 = blockIdx.y * 8;
    const float* x = (s == 0) ? x1 : (s == 1) ? x2 : x12;
    const float* xb = x + (size_t)b * CIN * HW;

    for (int pos = threadIdx.x; pos < 34 * 34; pos += 256) {
        const int row = pos / 34, col = pos % 34;
        const int gy = row - 1, gx = col - 1;
        half8_t v;
        if ((unsigned)gy < 32u && (unsigned)gx < 32u) {
            #pragma unroll
            for (int j = 0; j < 8; ++j)
                v[j] = (_Float16)xb[(size_t)(ci0 + j) * HW + gy * 32 + gx];
        } else {
            #pragma unroll
            for (int j = 0; j < 8; ++j) v[j] = (_Float16)0.f;
        }
        *reinterpret_cast<half8_t*>(&xt[((size_t)sb * 1156 + pos) * 64 + ci0]) = v;
    }
}

// ---------------------------------------------------------------------------
// Prep B: weights -> A-fragment layout wf[s][ct(12)][ks(36)][lane(64)][4] f16,
// with 0.25 q-scale folded in (co<64).
// ---------------------------------------------------------------------------
__global__ __launch_bounds__(256) void prep_wf_kernel(
    const float* __restrict__ w1, const float* __restrict__ w2,
    const float* __restrict__ w12, _Float16* __restrict__ wf)
{
    const int f = blockIdx.x * 256 + threadIdx.x;   // 82944 frags
    if (f >= 3 * 12 * 36 * 64) return;
    const int lane = f & 63;
    int r = f >> 6;
    const int ks = r % 36; r /= 36;
    const int ct = r % 12; const int s = r / 12;
    const float* w = (s == 0) ? w1 : (s == 1) ? w2 : w12;

    const int tap = ks >> 2;
    const int ci_b = (ks & 3) * 16 + (lane >> 4) * 4;
    const int co = ct * 16 + (lane & 15);
    const float scale = (co < 64) ? 0.25f : 1.f;

    half4_t v;
    #pragma unroll
    for (int j = 0; j < 4; ++j)
        v[j] = (_Float16)(w[((size_t)co * 64 + ci_b + j) * 9 + tap] * scale);
    *reinterpret_cast<half4_t*>(&wf[(size_t)f * 4]) = v;
}

// ---------------------------------------------------------------------------
// Kernel 1: implicit-GEMM 3x3 conv via MFMA (unchanged from round 3).
// ---------------------------------------------------------------------------
__global__ __launch_bounds__(256) void conv_mfma_kernel(
    const _Float16* __restrict__ xt, const _Float16* __restrict__ wf,
    const float* __restrict__ b1, const float* __restrict__ b2,
    const float* __restrict__ b12, float* __restrict__ qkv)
{
    __shared__ _Float16 xs[8704];        // 4*34*64
    const int strip = blockIdx.x;
    const int b = blockIdx.y, s = blockIdx.z;
    const int sb = s * Bn + b;
    const int tid = threadIdx.x;
    const int w = tid >> 6, lane = tid & 63, g = lane >> 4, lq = lane & 15;
    const int y0 = strip * 2;

    const half4_t* src = reinterpret_cast<const half4_t*>(
        xt + ((size_t)sb * 1156 + y0 * 34) * 64);
    for (int c = tid; c < 2176; c += 256) {
        const int cic = c & 15;
        const int colrow = c >> 4;
        const int xx = colrow % 34;
        const int lofs = colrow * 64 + ((cic ^ (xx & 15)) << 2);
        *reinterpret_cast<half4_t*>(&xs[lofs]) = src[c];
    }
    __syncthreads();

    f32x4 acc[3][4];
    #pragma unroll
    for (int cc = 0; cc < 3; ++cc)
        #pragma unroll
        for (int t = 0; t < 4; ++t) acc[cc][t] = (f32x4){0.f, 0.f, 0.f, 0.f};

    const _Float16* wfs = wf + ((size_t)(s * 12 + w * 3) * 36) * 256;

    #pragma unroll
    for (int tap = 0; tap < 9; ++tap) {
        const int ky = tap / 3, kx = tap % 3;
        #pragma unroll
        for (int sub = 0; sub < 4; ++sub) {
            const int ks = tap * 4 + sub;
            half4_t af[3];
            #pragma unroll
            for (int cc = 0; cc < 3; ++cc)
                af[cc] = *reinterpret_cast<const half4_t*>(
                    &wfs[((size_t)cc * 36 + ks) * 256 + lane * 4]);
            half4_t bf[4];
            #pragma unroll
            for (int t = 0; t < 4; ++t) {
                const int ry = (t >> 1) + ky;
                const int xx = (t & 1) * 16 + lq + kx;
                const int cichunk = sub * 4 + g;
                bf[t] = *reinterpret_cast<const half4_t*>(
                    &xs[(ry * 34 + xx) * 64 + ((cichunk ^ (xx & 15)) << 2)]);
            }
            #pragma unroll
            for (int cc = 0; cc < 3; ++cc)
                #pragma unroll
                for (int t = 0; t < 4; ++t)
                    acc[cc][t] = __builtin_amdgcn_mfma_f32_16x16x16f16(
                        af[cc], bf[t], acc[cc][t], 0, 0, 0);
        }
    }

    const float* bi = (s == 0) ? b1 : (s == 1) ? b2 : b12;
    float* outb = qkv + (size_t)sb * CQKV * HW;
    #pragma unroll
    for (int cc = 0; cc < 3; ++cc) {
        const int ct = w * 3 + cc;
        const float bsc = (ct < 4) ? 0.25f : 1.f;
        const f32x4 bv4 = *reinterpret_cast<const f32x4*>(&bi[ct * 16 + g * 4]);
        #pragma unroll
        for (int t = 0; t < 4; ++t) {
            const int px = strip * 64 + t * 16 + lq;
            #pragma unroll
            for (int r = 0; r < 4; ++r) {
                const int ch = ct * 16 + g * 4 + r;
                outb[(size_t)ch * HW + px] = acc[cc][t][r] + bsc * bv4[r];
            }
        }
    }
}

// ---------------------------------------------------------------------------
// Kernel 2: rel-logit precompute (unchanged).
// ---------------------------------------------------------------------------
__global__ __launch_bounds__(256) void qrel_kernel(
    const float* __restrict__ qkv,
    const float* __restrict__ relw, const float* __restrict__ relh,
    float* __restrict__ qrw, float* __restrict__ qrh)
{
    const int m  = blockIdx.x;          // 0..62
    const int bh = blockIdx.y;          // b*4+h
    const int b  = bh >> 2, h = bh & 3;

    float ww[16], wh[16];
    #pragma unroll
    for (int d = 0; d < 16; ++d) {
        ww[d] = relw[m * 16 + d];
        wh[d] = relh[m * 16 + d];
    }
    const float* qb = qkv + ((size_t)b * CQKV + h * 16) * HW;
    for (int i = threadIdx.x; i < HW; i += 256) {
        float sw = 0.f, sh = 0.f;
        #pragma unroll
        for (int d = 0; d < 16; ++d) {
            const float qv = qb[(size_t)d * HW + i];
            sw = fmaf(qv, ww[d], sw);
            sh = fmaf(qv, wh[d], sh);
        }
        qrw[((size_t)bh * 64 + m) * HW + i] = sw;
        qrh[((size_t)bh * 64 + m) * HW + i] = sh;
    }
}

// ---------------------------------------------------------------------------
// Kernel 3: MFMA flash attention — round-3 online softmax, upgraded:
//  * 512-thread blocks (8 waves, 128 queries) -> same 64KB LDS serves 2x
//    queries: 2 blocks/CU = 16 waves/CU (2x round-3 occupancy).
//  * 2 chunks (64 keys) per softmax iteration: serial max/exp/rescale chain
//    count 32 -> 16; the 4 score mfmas + 4 LDS reads pipeline.
//  * NO qrhc[] register cache (round-4 spill lesson); qrh loads stay in-loop.
// ---------------------------------------------------------------------------
__global__ __launch_bounds__(512, 4) void attn_mfma_kernel(
    const float* __restrict__ qkv,
    const float* __restrict__ qrw, const float* __restrict__ qrh,
    float* __restrict__ o)
{
    __shared__ _Float16 kf_lds[16384];   // 32 KB: K fragments
    __shared__ _Float16 vf_lds[16384];   // 32 KB: V fragments

    const int S   = blockIdx.z;
    const int bh  = blockIdx.y;
    const int b   = bh >> 2, hd = bh & 3;
    const int tid = threadIdx.x;
    const int w    = tid >> 6;           // wave 0..7
    const int lane = tid & 63;
    const int g    = lane >> 4;
    const int lq   = lane & 15;
    const size_t SS = (size_t)Bn * CQKV * HW;

    const float* qsrc = qkv + S * SS + ((size_t)b * CQKV + hd * 16) * HW;
    const float* vsrc = qkv + S * SS + ((size_t)b * CQKV + 128 + hd * 16) * HW;
    const float* k1p;
    const float* k2p;
    if (S == 2) {
        k1p = qkv + 0 * SS + ((size_t)b * CQKV + 64 + hd * 16) * HW;
        k2p = qkv + 1 * SS + ((size_t)b * CQKV + 64 + hd * 16) * HW;
    } else {
        k1p = qkv + 2 * SS + ((size_t)b * CQKV + 64 + hd * 16) * HW;
        k2p = k1p;
    }

    // ---- stage K,V as MFMA fragments (f32 global -> f16 LDS) -------------
    #pragma unroll 4
    for (int it = 0; it < 8; ++it) {
        const int idx = it * 512 + tid;          // 0..4095
        const int kt  = idx >> 6, l = idx & 63;
        const int row = l & 15;
        const int d0  = (l >> 4) * 4;
        const int lofs = (kt >> 1) * 512 + l * 8 + (kt & 1) * 4;

        const int key = kt * 16 + row;
        half4_t kh;
        #pragma unroll
        for (int j = 0; j < 4; ++j) {
            float x = k1p[(size_t)(d0 + j) * HW + key];
            if (S == 2) x -= k2p[(size_t)(d0 + j) * HW + key];
            kh[j] = (_Float16)x;
        }
        *reinterpret_cast<half4_t*>(&kf_lds[lofs]) = kh;

        const f32x4 vv = *reinterpret_cast<const f32x4*>(
            &vsrc[(size_t)row * HW + kt * 16 + d0]);
        half4_t vh;
        #pragma unroll
        for (int j = 0; j < 4; ++j) vh[j] = (_Float16)vv[j];
        *reinterpret_cast<half4_t*>(&vf_lds[lofs]) = vh;
    }

    // ---- per-wave Q fragment + rel-w register cache -----------------------
    const int qb0 = blockIdx.x * 128 + w * 16;
    const int i   = qb0 + lq;
    const int x1  = i & 31, y1 = i >> 5;

    half4_t qf;
    #pragma unroll
    for (int j = 0; j < 4; ++j)
        qf[j] = (_Float16)qsrc[(size_t)(g * 4 + j) * HW + i];

    float rwc0[4], rwc1[4];
    if (S == 0) {
        #pragma unroll
        for (int r = 0; r < 4; ++r) {
            rwc0[r] = qrw[((size_t)bh * 64 + (g * 4 + r      - x1 + 31)) * HW + i];
            rwc1[r] = qrw[((size_t)bh * 64 + (g * 4 + r + 16 - x1 + 31)) * HW + i];
        }
    }

    __syncthreads();

    f32x4 acc = {0.f, 0.f, 0.f, 0.f};
    float m = -1e30f, lsum = 0.f;
    const f32x4 zero4 = {0.f, 0.f, 0.f, 0.f};

    // ---- online-softmax sweep: 16 iters x 64 keys --------------------------
    for (int c = 0; c < 32; c += 2) {
        const half8_t kk0 = *reinterpret_cast<const half8_t*>(&kf_lds[c * 512 + lane * 8]);
        const half8_t kk1 = *reinterpret_cast<const half8_t*>(&kf_lds[(c + 1) * 512 + lane * 8]);
        const half8_t vv0 = *reinterpret_cast<const half8_t*>(&vf_lds[c * 512 + lane * 8]);
        const half8_t vv1 = *reinterpret_cast<const half8_t*>(&vf_lds[(c + 1) * 512 + lane * 8]);
        float rh0 = 0.f, rh1 = 0.f;
        if (S == 0) {
            rh0 = qrh[((size_t)bh * 64 + (c     - y1 + 31)) * HW + i];
            rh1 = qrh[((size_t)bh * 64 + (c + 1 - y1 + 31)) * HW + i];
        }

        f32x4 s0 = __builtin_amdgcn_mfma_f32_16x16x16f16(
            __builtin_shufflevector(kk0, kk0, 0, 1, 2, 3), qf, zero4, 0, 0, 0);
        f32x4 s1 = __builtin_amdgcn_mfma_f32_16x16x16f16(
            __builtin_shufflevector(kk0, kk0, 4, 5, 6, 7), qf, zero4, 0, 0, 0);
        f32x4 s2 = __builtin_amdgcn_mfma_f32_16x16x16f16(
            __builtin_shufflevector(kk1, kk1, 0, 1, 2, 3), qf, zero4, 0, 0, 0);
        f32x4 s3 = __builtin_amdgcn_mfma_f32_16x16x16f16(
            __builtin_shufflevector(kk1, kk1, 4, 5, 6, 7), qf, zero4, 0, 0, 0);

        if (S == 0) {
            #pragma unroll
            for (int r = 0; r < 4; ++r) {
                s0[r] += rh0 + rwc0[r];
                s1[r] += rh0 + rwc1[r];
                s2[r] += rh1 + rwc0[r];
                s3[r] += rh1 + rwc1[r];
            }
        }

        float vmax = fmaxf(
            fmaxf(fmaxf(fmaxf(s0[0], s0[1]), fmaxf(s0[2], s0[3])),
                  fmaxf(fmaxf(s1[0], s1[1]), fmaxf(s1[2], s1[3]))),
            fmaxf(fmaxf(fmaxf(s2[0], s2[1]), fmaxf(s2[2], s2[3])),
                  fmaxf(fmaxf(s3[0], s3[1]), fmaxf(s3[2], s3[3]))));
        vmax = fmaxf(vmax, __shfl_xor(vmax, 16));
        vmax = fmaxf(vmax, __shfl_xor(vmax, 32));

        const float mnew = fmaxf(m, vmax);
        const float fsc  = __expf(m - mnew);
        m = mnew;
        lsum *= fsc;
        acc *= fsc;

        half4_t pa, pb, pc, pd;
        #pragma unroll
        for (int r = 0; r < 4; ++r) {
            const float p0 = __expf(s0[r] - mnew);
            const float p1 = __expf(s1[r] - mnew);
            const float p2 = __expf(s2[r] - mnew);
            const float p3 = __expf(s3[r] - mnew);
            lsum += (p0 + p1) + (p2 + p3);
            pa[r] = (_Float16)p0;
            pb[r] = (_Float16)p1;
            pc[r] = (_Float16)p2;
            pd[r] = (_Float16)p3;
        }

        acc = __builtin_amdgcn_mfma_f32_16x16x16f16(
            __builtin_shufflevector(vv0, vv0, 0, 1, 2, 3), pa, acc, 0, 0, 0);
        acc = __builtin_amdgcn_mfma_f32_16x16x16f16(
            __builtin_shufflevector(vv0, vv0, 4, 5, 6, 7), pb, acc, 0, 0, 0);
        acc = __builtin_amdgcn_mfma_f32_16x16x16f16(
            __builtin_shufflevector(vv1, vv1, 0, 1, 2, 3), pc, acc, 0, 0, 0);
        acc = __builtin_amdgcn_mfma_f32_16x16x16f16(
            __builtin_shufflevector(vv1, vv1, 4, 5, 6, 7), pd, acc, 0, 0, 0);
    }

    lsum += __shfl_xor(lsum, 16);
    lsum += __shfl_xor(lsum, 32);
    const float inv = 1.f / lsum;

    float* op = o + ((((size_t)S * Bn + b) * NHh + hd) * HW) * 16;
    f32x4 res;
    #pragma unroll
    for (int r = 0; r < 4; ++r) res[r] = acc[r] * inv;
    *reinterpret_cast<f32x4*>(&op[(size_t)i * 16 + g * 4]) = res;
}

// ---------------------------------------------------------------------------
// Kernel 4: 1x1 output conv (unchanged).
// ---------------------------------------------------------------------------
__global__ __launch_bounds__(256) void out_conv_kernel(
    const float* __restrict__ o, const float* __restrict__ wout,
    const float* __restrict__ bout, float* __restrict__ out)
{
    const int co = blockIdx.x;
    const int sb = blockIdx.y;
    const int tid = threadIdx.x;
    const float* ob = o + (size_t)sb * 64 * HW;

    float acc[4] = {0.f, 0.f, 0.f, 0.f};
    for (int c = 0; c < 64; ++c) {
        const float wv = wout[co * 64 + c];
        #pragma unroll
        for (int p = 0; p < 4; ++p)
            acc[p] = fmaf(wv, ob[(size_t)c * HW + tid + p * 256], acc[p]);
    }
    const float bv = bout[co];
    #pragma unroll
    for (int p = 0; p < 4; ++p)
        out[((size_t)sb * 64 + co) * HW + tid + p * 256] = acc[p] + bv;
}

// ---------------------------------------------------------------------------
extern "C" void kernel_launch(void* const* d_in, const int* in_sizes, int n_in,
                              void* d_out, int out_size, void* d_ws, size_t ws_size,
                              hipStream_t stream)
{
    const float* x1   = (const float*)d_in[0];
    const float* x2   = (const float*)d_in[1];
    const float* x12  = (const float*)d_in[2];
    const float* wq1  = (const float*)d_in[3];
    const float* bq1  = (const float*)d_in[4];
    const float* wq2  = (const float*)d_in[5];
    const float* bq2  = (const float*)d_in[6];
    const float* wq12 = (const float*)d_in[7];
    const float* bq12 = (const float*)d_in[8];
    const float* wout = (const float*)d_in[9];
    const float* bout = (const float*)d_in[10];
    const float* relw = (const float*)d_in[11];
    const float* relh = (const float*)d_in[12];

    float* ws  = (float*)d_ws;
    float* qkv = ws;                                   // 3*8*192*1024
    float* qrw = qkv + (size_t)3 * Bn * CQKV * HW;     // 32*64*1024
    float* qrh = qrw + (size_t)32 * 64 * HW;
    float* o   = qrh + (size_t)32 * 64 * HW;           // 3*8*4*1024*16

    _Float16* xt = (_Float16*)qrw;                     // aliases (dead before qrel)
    _Float16* wf = (_Float16*)qrh;

    prep_xt_kernel<<<dim3(24, 8), 256, 0, stream>>>(x1, x2, x12, xt);
    prep_wf_kernel<<<dim3(324), 256, 0, stream>>>(wq1, wq2, wq12, wf);

    conv_mfma_kernel<<<dim3(16, 8, 3), 256, 0, stream>>>(
        xt, wf, bq1, bq2, bq12, qkv);

    qrel_kernel<<<dim3(63, 32), 256, 0, stream>>>(qkv, relw, relh, qrw, qrh);

    attn_mfma_kernel<<<dim3(8, 32, 3), 512, 0, stream>>>(qkv, qrw, qrh, o);

    out_conv_kernel<<<dim3(64, 24), 256, 0, stream>>>(o, wout, bout, (float*)d_out);
}

// Round 7
// 99.663 us; speedup vs baseline: 2.2575x; 1.0579x over previous
//
#include <hip/hip_runtime.h>
#include <math.h>

#define Bn 8
#define CIN 64
#define HH 32
#define WW 32
#define HW 1024
#define CQKV 192
#define NHh 4
#define DKHd 16
#define DVHd 16

typedef _Float16 half4_t __attribute__((ext_vector_type(4)));
typedef _Float16 half8_t __attribute__((ext_vector_type(8)));
typedef float f32x4 __attribute__((ext_vector_type(4)));

// ---------------------------------------------------------------------------
// Prep A: x (f32, [sb][ci][32][32]) -> xt (f16, [sb][34][34][64]) zero-padded.
// ---------------------------------------------------------------------------
__global__ __launch_bounds__(256) void prep_xt_kernel(
    const float* __restrict__ x1, const float* __restrict__ x2,
    const float* __restrict__ x12, _Float16* __restrict__ xt)
{
    const int sb = blockIdx.x;           // s*8 + b
    const int s  = sb >> 3, b = sb & 7;
    const int ci0 = blockIdx.y * 8;
    const float* x = (s == 0) ? x1 : (s == 1) ? x2 : x12;
    const float* xb = x + (size_t)b * CIN * HW;

    for (int pos = threadIdx.x; pos < 34 * 34; pos += 256) {
        const int row = pos / 34, col = pos % 34;
        const int gy = row - 1, gx = col - 1;
        half8_t v;
        if ((unsigned)gy < 32u && (unsigned)gx < 32u) {
            #pragma unroll
            for (int j = 0; j < 8; ++j)
                v[j] = (_Float16)xb[(size_t)(ci0 + j) * HW + gy * 32 + gx];
        } else {
            #pragma unroll
            for (int j = 0; j < 8; ++j) v[j] = (_Float16)0.f;
        }
        *reinterpret_cast<half8_t*>(&xt[((size_t)sb * 1156 + pos) * 64 + ci0]) = v;
    }
}

// ---------------------------------------------------------------------------
// Prep B: weights -> A-fragment layout wf[s][ct(12)][ks(36)][lane(64)][4] f16,
// with 0.25 q-scale folded in (co<64).
// ---------------------------------------------------------------------------
__global__ __launch_bounds__(256) void prep_wf_kernel(
    const float* __restrict__ w1, const float* __restrict__ w2,
    const float* __restrict__ w12, _Float16* __restrict__ wf)
{
    const int f = blockIdx.x * 256 + threadIdx.x;   // 82944 frags
    if (f >= 3 * 12 * 36 * 64) return;
    const int lane = f & 63;
    int r = f >> 6;
    const int ks = r % 36; r /= 36;
    const int ct = r % 12; const int s = r / 12;
    const float* w = (s == 0) ? w1 : (s == 1) ? w2 : w12;

    const int tap = ks >> 2;
    const int ci_b = (ks & 3) * 16 + (lane >> 4) * 4;
    const int co = ct * 16 + (lane & 15);
    const float scale = (co < 64) ? 0.25f : 1.f;

    half4_t v;
    #pragma unroll
    for (int j = 0; j < 4; ++j)
        v[j] = (_Float16)(w[((size_t)co * 64 + ci_b + j) * 9 + tap] * scale);
    *reinterpret_cast<half4_t*>(&wf[(size_t)f * 4]) = v;
}

// ---------------------------------------------------------------------------
// Kernel 1: implicit-GEMM 3x3 conv via MFMA (unchanged).
// ---------------------------------------------------------------------------
__global__ __launch_bounds__(256) void conv_mfma_kernel(
    const _Float16* __restrict__ xt, const _Float16* __restrict__ wf,
    const float* __restrict__ b1, const float* __restrict__ b2,
    const float* __restrict__ b12, float* __restrict__ qkv)
{
    __shared__ _Float16 xs[8704];        // 4*34*64
    const int strip = blockIdx.x;
    const int b = blockIdx.y, s = blockIdx.z;
    const int sb = s * Bn + b;
    const int tid = threadIdx.x;
    const int w = tid >> 6, lane = tid & 63, g = lane >> 4, lq = lane & 15;
    const int y0 = strip * 2;

    const half4_t* src = reinterpret_cast<const half4_t*>(
        xt + ((size_t)sb * 1156 + y0 * 34) * 64);
    for (int c = tid; c < 2176; c += 256) {
        const int cic = c & 15;
        const int colrow = c >> 4;
        const int xx = colrow % 34;
        const int lofs = colrow * 64 + ((cic ^ (xx & 15)) << 2);
        *reinterpret_cast<half4_t*>(&xs[lofs]) = src[c];
    }
    __syncthreads();

    f32x4 acc[3][4];
    #pragma unroll
    for (int cc = 0; cc < 3; ++cc)
        #pragma unroll
        for (int t = 0; t < 4; ++t) acc[cc][t] = (f32x4){0.f, 0.f, 0.f, 0.f};

    const _Float16* wfs = wf + ((size_t)(s * 12 + w * 3) * 36) * 256;

    #pragma unroll
    for (int tap = 0; tap < 9; ++tap) {
        const int ky = tap / 3, kx = tap % 3;
        #pragma unroll
        for (int sub = 0; sub < 4; ++sub) {
            const int ks = tap * 4 + sub;
            half4_t af[3];
            #pragma unroll
            for (int cc = 0; cc < 3; ++cc)
                af[cc] = *reinterpret_cast<const half4_t*>(
                    &wfs[((size_t)cc * 36 + ks) * 256 + lane * 4]);
            half4_t bf[4];
            #pragma unroll
            for (int t = 0; t < 4; ++t) {
                const int ry = (t >> 1) + ky;
                const int xx = (t & 1) * 16 + lq + kx;
                const int cichunk = sub * 4 + g;
                bf[t] = *reinterpret_cast<const half4_t*>(
                    &xs[(ry * 34 + xx) * 64 + ((cichunk ^ (xx & 15)) << 2)]);
            }
            #pragma unroll
            for (int cc = 0; cc < 3; ++cc)
                #pragma unroll
                for (int t = 0; t < 4; ++t)
                    acc[cc][t] = __builtin_amdgcn_mfma_f32_16x16x16f16(
                        af[cc], bf[t], acc[cc][t], 0, 0, 0);
        }
    }

    const float* bi = (s == 0) ? b1 : (s == 1) ? b2 : b12;
    float* outb = qkv + (size_t)sb * CQKV * HW;
    #pragma unroll
    for (int cc = 0; cc < 3; ++cc) {
        const int ct = w * 3 + cc;
        const float bsc = (ct < 4) ? 0.25f : 1.f;
        const f32x4 bv4 = *reinterpret_cast<const f32x4*>(&bi[ct * 16 + g * 4]);
        #pragma unroll
        for (int t = 0; t < 4; ++t) {
            const int px = strip * 64 + t * 16 + lq;
            #pragma unroll
            for (int r = 0; r < 4; ++r) {
                const int ch = ct * 16 + g * 4 + r;
                outb[(size_t)ch * HW + px] = acc[cc][t][r] + bsc * bv4[r];
            }
        }
    }
}

// ---------------------------------------------------------------------------
// Kernel 2: rel-logit precompute — now writes f16 (half the traffic).
// ---------------------------------------------------------------------------
__global__ __launch_bounds__(256) void qrel_kernel(
    const float* __restrict__ qkv,
    const float* __restrict__ relw, const float* __restrict__ relh,
    _Float16* __restrict__ qrw, _Float16* __restrict__ qrh)
{
    const int m  = blockIdx.x;          // 0..62
    const int bh = blockIdx.y;          // b*4+h
    const int b  = bh >> 2, h = bh & 3;

    float ww[16], wh[16];
    #pragma unroll
    for (int d = 0; d < 16; ++d) {
        ww[d] = relw[m * 16 + d];
        wh[d] = relh[m * 16 + d];
    }
    const float* qb = qkv + ((size_t)b * CQKV + h * 16) * HW;
    for (int i = threadIdx.x; i < HW; i += 256) {
        float sw = 0.f, sh = 0.f;
        #pragma unroll
        for (int d = 0; d < 16; ++d) {
            const float qv = qb[(size_t)d * HW + i];
            sw = fmaf(qv, ww[d], sw);
            sh = fmaf(qv, wh[d], sh);
        }
        qrw[((size_t)bh * 64 + m) * HW + i] = (_Float16)sw;
        qrh[((size_t)bh * 64 + m) * HW + i] = (_Float16)sh;
    }
}

// ---------------------------------------------------------------------------
// Kernel 3: MFMA flash attention.
// Round 6: grid (32 bh, 8 qb, 3 S) so the 8 q-blocks sharing K/V have linear
// ids differing by 32 -> same XCD (id%8) -> K/V served from one L2.
// Defer-max (T13, THR=8): skip cross-lane max + rescale unless some score
// exceeds m+8; p <= e^8 = 2981 fits f16. First iter always updates (m=-1e30).
// qrw/qrh read as f16.
// ---------------------------------------------------------------------------
__global__ __launch_bounds__(512, 4) void attn_mfma_kernel(
    const float* __restrict__ qkv,
    const _Float16* __restrict__ qrw, const _Float16* __restrict__ qrh,
    float* __restrict__ o)
{
    __shared__ _Float16 kf_lds[16384];   // 32 KB: K fragments
    __shared__ _Float16 vf_lds[16384];   // 32 KB: V fragments

    const int S   = blockIdx.z;
    const int bh  = blockIdx.x;          // XCD-locality: bh fastest-varying
    const int qb  = blockIdx.y;
    const int b   = bh >> 2, hd = bh & 3;
    const int tid = threadIdx.x;
    const int w    = tid >> 6;           // wave 0..7
    const int lane = tid & 63;
    const int g    = lane >> 4;
    const int lq   = lane & 15;
    const size_t SS = (size_t)Bn * CQKV * HW;

    const float* qsrc = qkv + S * SS + ((size_t)b * CQKV + hd * 16) * HW;
    const float* vsrc = qkv + S * SS + ((size_t)b * CQKV + 128 + hd * 16) * HW;
    const float* k1p;
    const float* k2p;
    if (S == 2) {
        k1p = qkv + 0 * SS + ((size_t)b * CQKV + 64 + hd * 16) * HW;
        k2p = qkv + 1 * SS + ((size_t)b * CQKV + 64 + hd * 16) * HW;
    } else {
        k1p = qkv + 2 * SS + ((size_t)b * CQKV + 64 + hd * 16) * HW;
        k2p = k1p;
    }

    // ---- stage K,V as MFMA fragments (f32 global -> f16 LDS) -------------
    #pragma unroll 4
    for (int it = 0; it < 8; ++it) {
        const int idx = it * 512 + tid;          // 0..4095
        const int kt  = idx >> 6, l = idx & 63;
        const int row = l & 15;
        const int d0  = (l >> 4) * 4;
        const int lofs = (kt >> 1) * 512 + l * 8 + (kt & 1) * 4;

        const int key = kt * 16 + row;
        half4_t kh;
        #pragma unroll
        for (int j = 0; j < 4; ++j) {
            float x = k1p[(size_t)(d0 + j) * HW + key];
            if (S == 2) x -= k2p[(size_t)(d0 + j) * HW + key];
            kh[j] = (_Float16)x;
        }
        *reinterpret_cast<half4_t*>(&kf_lds[lofs]) = kh;

        const f32x4 vv = *reinterpret_cast<const f32x4*>(
            &vsrc[(size_t)row * HW + kt * 16 + d0]);
        half4_t vh;
        #pragma unroll
        for (int j = 0; j < 4; ++j) vh[j] = (_Float16)vv[j];
        *reinterpret_cast<half4_t*>(&vf_lds[lofs]) = vh;
    }

    // ---- per-wave Q fragment + rel-w register cache -----------------------
    const int qb0 = qb * 128 + w * 16;
    const int i   = qb0 + lq;
    const int x1  = i & 31, y1 = i >> 5;

    half4_t qf;
    #pragma unroll
    for (int j = 0; j < 4; ++j)
        qf[j] = (_Float16)qsrc[(size_t)(g * 4 + j) * HW + i];

    float rwc0[4], rwc1[4];
    if (S == 0) {
        #pragma unroll
        for (int r = 0; r < 4; ++r) {
            rwc0[r] = (float)qrw[((size_t)bh * 64 + (g * 4 + r      - x1 + 31)) * HW + i];
            rwc1[r] = (float)qrw[((size_t)bh * 64 + (g * 4 + r + 16 - x1 + 31)) * HW + i];
        }
    }

    __syncthreads();

    f32x4 acc = {0.f, 0.f, 0.f, 0.f};
    float m = -1e30f, lsum = 0.f;
    const f32x4 zero4 = {0.f, 0.f, 0.f, 0.f};

    // ---- online-softmax sweep: 16 iters x 64 keys, defer-max --------------
    for (int c = 0; c < 32; c += 2) {
        const half8_t kk0 = *reinterpret_cast<const half8_t*>(&kf_lds[c * 512 + lane * 8]);
        const half8_t kk1 = *reinterpret_cast<const half8_t*>(&kf_lds[(c + 1) * 512 + lane * 8]);
        const half8_t vv0 = *reinterpret_cast<const half8_t*>(&vf_lds[c * 512 + lane * 8]);
        const half8_t vv1 = *reinterpret_cast<const half8_t*>(&vf_lds[(c + 1) * 512 + lane * 8]);
        float rh0 = 0.f, rh1 = 0.f;
        if (S == 0) {
            rh0 = (float)qrh[((size_t)bh * 64 + (c     - y1 + 31)) * HW + i];
            rh1 = (float)qrh[((size_t)bh * 64 + (c + 1 - y1 + 31)) * HW + i];
        }

        f32x4 s0 = __builtin_amdgcn_mfma_f32_16x16x16f16(
            __builtin_shufflevector(kk0, kk0, 0, 1, 2, 3), qf, zero4, 0, 0, 0);
        f32x4 s1 = __builtin_amdgcn_mfma_f32_16x16x16f16(
            __builtin_shufflevector(kk0, kk0, 4, 5, 6, 7), qf, zero4, 0, 0, 0);
        f32x4 s2 = __builtin_amdgcn_mfma_f32_16x16x16f16(
            __builtin_shufflevector(kk1, kk1, 0, 1, 2, 3), qf, zero4, 0, 0, 0);
        f32x4 s3 = __builtin_amdgcn_mfma_f32_16x16x16f16(
            __builtin_shufflevector(kk1, kk1, 4, 5, 6, 7), qf, zero4, 0, 0, 0);

        if (S == 0) {
            #pragma unroll
            for (int r = 0; r < 4; ++r) {
                s0[r] += rh0 + rwc0[r];
                s1[r] += rh0 + rwc1[r];
                s2[r] += rh1 + rwc0[r];
                s3[r] += rh1 + rwc1[r];
            }
        }

        // per-lane max (max3-friendly triples)
        float a0 = fmaxf(fmaxf(s0[0], s0[1]), s0[2]);
        float a1 = fmaxf(fmaxf(s0[3], s1[0]), s1[1]);
        float a2 = fmaxf(fmaxf(s1[2], s1[3]), s2[0]);
        float a3 = fmaxf(fmaxf(s2[1], s2[2]), s2[3]);
        float a4 = fmaxf(fmaxf(s3[0], s3[1]), s3[2]);
        float vmax = fmaxf(fmaxf(fmaxf(a0, a1), fmaxf(a2, a3)),
                           fmaxf(a4, s3[3]));

        // defer-max: only reduce + rescale when some score exceeds m + 8
        if (!__all(vmax <= m + 8.f)) {
            float wmax = fmaxf(vmax, __shfl_xor(vmax, 16));
            wmax = fmaxf(wmax, __shfl_xor(wmax, 32));
            const float mnew = fmaxf(m, wmax);
            const float fsc  = __expf(m - mnew);
            m = mnew;
            lsum *= fsc;
            acc *= fsc;
        }

        half4_t pa, pb, pc, pd;
        float ps = 0.f;
        #pragma unroll
        for (int r = 0; r < 4; ++r) {
            const float p0 = __expf(s0[r] - m);
            const float p1 = __expf(s1[r] - m);
            const float p2 = __expf(s2[r] - m);
            const float p3 = __expf(s3[r] - m);
            ps += (p0 + p1) + (p2 + p3);
            pa[r] = (_Float16)p0;
            pb[r] = (_Float16)p1;
            pc[r] = (_Float16)p2;
            pd[r] = (_Float16)p3;
        }
        lsum += ps;

        acc = __builtin_amdgcn_mfma_f32_16x16x16f16(
            __builtin_shufflevector(vv0, vv0, 0, 1, 2, 3), pa, acc, 0, 0, 0);
        acc = __builtin_amdgcn_mfma_f32_16x16x16f16(
            __builtin_shufflevector(vv0, vv0, 4, 5, 6, 7), pb, acc, 0, 0, 0);
        acc = __builtin_amdgcn_mfma_f32_16x16x16f16(
            __builtin_shufflevector(vv1, vv1, 0, 1, 2, 3), pc, acc, 0, 0, 0);
        acc = __builtin_amdgcn_mfma_f32_16x16x16f16(
            __builtin_shufflevector(vv1, vv1, 4, 5, 6, 7), pd, acc, 0, 0, 0);
    }

    lsum += __shfl_xor(lsum, 16);
    lsum += __shfl_xor(lsum, 32);
    const float inv = 1.f / lsum;

    float* op = o + ((((size_t)S * Bn + b) * NHh + hd) * HW) * 16;
    f32x4 res;
    #pragma unroll
    for (int r = 0; r < 4; ++r) res[r] = acc[r] * inv;
    *reinterpret_cast<f32x4*>(&op[(size_t)i * 16 + g * 4]) = res;
}

// ---------------------------------------------------------------------------
// Kernel 4: 1x1 output conv (unchanged).
// ---------------------------------------------------------------------------
__global__ __launch_bounds__(256) void out_conv_kernel(
    const float* __restrict__ o, const float* __restrict__ wout,
    const float* __restrict__ bout, float* __restrict__ out)
{
    const int co = blockIdx.x;
    const int sb = blockIdx.y;
    const int tid = threadIdx.x;
    const float* ob = o + (size_t)sb * 64 * HW;

    float acc[4] = {0.f, 0.f, 0.f, 0.f};
    for (int c = 0; c < 64; ++c) {
        const float wv = wout[co * 64 + c];
        #pragma unroll
        for (int p = 0; p < 4; ++p)
            acc[p] = fmaf(wv, ob[(size_t)c * HW + tid + p * 256], acc[p]);
    }
    const float bv = bout[co];
    #pragma unroll
    for (int p = 0; p < 4; ++p)
        out[((size_t)sb * 64 + co) * HW + tid + p * 256] = acc[p] + bv;
}

// ---------------------------------------------------------------------------
extern "C" void kernel_launch(void* const* d_in, const int* in_sizes, int n_in,
                              void* d_out, int out_size, void* d_ws, size_t ws_size,
                              hipStream_t stream)
{
    const float* x1   = (const float*)d_in[0];
    const float* x2   = (const float*)d_in[1];
    const float* x12  = (const float*)d_in[2];
    const float* wq1  = (const float*)d_in[3];
    const float* bq1  = (const float*)d_in[4];
    const float* wq2  = (const float*)d_in[5];
    const float* bq2  = (const float*)d_in[6];
    const float* wq12 = (const float*)d_in[7];
    const float* bq12 = (const float*)d_in[8];
    const float* wout = (const float*)d_in[9];
    const float* bout = (const float*)d_in[10];
    const float* relw = (const float*)d_in[11];
    const float* relh = (const float*)d_in[12];

    float* ws  = (float*)d_ws;
    float* qkv = ws;                                    // 4,718,592 f
    float* o   = qkv + (size_t)3 * Bn * CQKV * HW;      // 1,572,864 f
    _Float16* qrw = (_Float16*)(o + (size_t)3 * Bn * 64 * HW / 4 * 4 /* = 1,572,864 */);
    // qrw: 32*64*1024 halves = 2,097,152 h (4 MB); qrh follows.
    _Float16* qrh = qrw + (size_t)32 * 64 * HW;

    // xt (1,775,616 h) aliases qrw (2,097,152 h); wf (331,776 h) aliases qrh.
    _Float16* xt = qrw;
    _Float16* wf = qrh;

    prep_xt_kernel<<<dim3(24, 8), 256, 0, stream>>>(x1, x2, x12, xt);
    prep_wf_kernel<<<dim3(324), 256, 0, stream>>>(wq1, wq2, wq12, wf);

    conv_mfma_kernel<<<dim3(16, 8, 3), 256, 0, stream>>>(
        xt, wf, bq1, bq2, bq12, qkv);

    qrel_kernel<<<dim3(63, 32), 256, 0, stream>>>(qkv, relw, relh, qrw, qrh);

    attn_mfma_kernel<<<dim3(32, 8, 3), 512, 0, stream>>>(qkv, qrw, qrh, o);

    out_conv_kernel<<<dim3(64, 24), 256, 0, stream>>>(o, wout, bout, (float*)d_out);
}

// Round 8
// 91.546 us; speedup vs baseline: 2.4576x; 1.0887x over previous
//
#include <hip/hip_runtime.h>
#include <math.h>

#define Bn 8
#define CIN 64
#define HH 32
#define WW 32
#define HW 1024
#define CQKV 192
#define NHh 4
#define DKHd 16
#define DVHd 16

typedef _Float16 half4_t __attribute__((ext_vector_type(4)));
typedef _Float16 half8_t __attribute__((ext_vector_type(8)));
typedef float f32x4 __attribute__((ext_vector_type(4)));

// ---------------------------------------------------------------------------
// Prep A: x (f32, [sb][ci][32][32]) -> xt (f16, [sb][34][34][64]) zero-padded.
// ---------------------------------------------------------------------------
__global__ __launch_bounds__(256) void prep_xt_kernel(
    const float* __restrict__ x1, const float* __restrict__ x2,
    const float* __restrict__ x12, _Float16* __restrict__ xt)
{
    const int sb = blockIdx.x;           // s*8 + b
    const int s  = sb >> 3, b = sb & 7;
    const int ci0 = blockIdx.y * 8;
    const float* x = (s == 0) ? x1 : (s == 1) ? x2 : x12;
    const float* xb = x + (size_t)b * CIN * HW;

    for (int pos = threadIdx.x; pos < 34 * 34; pos += 256) {
        const int row = pos / 34, col = pos % 34;
        const int gy = row - 1, gx = col - 1;
        half8_t v;
        if ((unsigned)gy < 32u && (unsigned)gx < 32u) {
            #pragma unroll
            for (int j = 0; j < 8; ++j)
                v[j] = (_Float16)xb[(size_t)(ci0 + j) * HW + gy * 32 + gx];
        } else {
            #pragma unroll
            for (int j = 0; j < 8; ++j) v[j] = (_Float16)0.f;
        }
        *reinterpret_cast<half8_t*>(&xt[((size_t)sb * 1156 + pos) * 64 + ci0]) = v;
    }
}

// ---------------------------------------------------------------------------
// Prep B: weights -> A-fragment layout wf[s][ct(12)][ks(36)][lane(64)][4] f16.
// ---------------------------------------------------------------------------
__global__ __launch_bounds__(256) void prep_wf_kernel(
    const float* __restrict__ w1, const float* __restrict__ w2,
    const float* __restrict__ w12, _Float16* __restrict__ wf)
{
    const int f = blockIdx.x * 256 + threadIdx.x;   // 82944 frags
    if (f >= 3 * 12 * 36 * 64) return;
    const int lane = f & 63;
    int r = f >> 6;
    const int ks = r % 36; r /= 36;
    const int ct = r % 12; const int s = r / 12;
    const float* w = (s == 0) ? w1 : (s == 1) ? w2 : w12;

    const int tap = ks >> 2;
    const int ci_b = (ks & 3) * 16 + (lane >> 4) * 4;
    const int co = ct * 16 + (lane & 15);
    const float scale = (co < 64) ? 0.25f : 1.f;

    half4_t v;
    #pragma unroll
    for (int j = 0; j < 4; ++j)
        v[j] = (_Float16)(w[((size_t)co * 64 + ci_b + j) * 9 + tap] * scale);
    *reinterpret_cast<half4_t*>(&wf[(size_t)f * 4]) = v;
}

// ---------------------------------------------------------------------------
// Kernel 1: implicit-GEMM 3x3 conv via MFMA. Output now written as f16.
// ---------------------------------------------------------------------------
__global__ __launch_bounds__(256) void conv_mfma_kernel(
    const _Float16* __restrict__ xt, const _Float16* __restrict__ wf,
    const float* __restrict__ b1, const float* __restrict__ b2,
    const float* __restrict__ b12, _Float16* __restrict__ qkv)
{
    __shared__ _Float16 xs[8704];        // 4*34*64
    const int strip = blockIdx.x;
    const int b = blockIdx.y, s = blockIdx.z;
    const int sb = s * Bn + b;
    const int tid = threadIdx.x;
    const int w = tid >> 6, lane = tid & 63, g = lane >> 4, lq = lane & 15;
    const int y0 = strip * 2;

    const half4_t* src = reinterpret_cast<const half4_t*>(
        xt + ((size_t)sb * 1156 + y0 * 34) * 64);
    for (int c = tid; c < 2176; c += 256) {
        const int cic = c & 15;
        const int colrow = c >> 4;
        const int xx = colrow % 34;
        const int lofs = colrow * 64 + ((cic ^ (xx & 15)) << 2);
        *reinterpret_cast<half4_t*>(&xs[lofs]) = src[c];
    }
    __syncthreads();

    f32x4 acc[3][4];
    #pragma unroll
    for (int cc = 0; cc < 3; ++cc)
        #pragma unroll
        for (int t = 0; t < 4; ++t) acc[cc][t] = (f32x4){0.f, 0.f, 0.f, 0.f};

    const _Float16* wfs = wf + ((size_t)(s * 12 + w * 3) * 36) * 256;

    #pragma unroll
    for (int tap = 0; tap < 9; ++tap) {
        const int ky = tap / 3, kx = tap % 3;
        #pragma unroll
        for (int sub = 0; sub < 4; ++sub) {
            const int ks = tap * 4 + sub;
            half4_t af[3];
            #pragma unroll
            for (int cc = 0; cc < 3; ++cc)
                af[cc] = *reinterpret_cast<const half4_t*>(
                    &wfs[((size_t)cc * 36 + ks) * 256 + lane * 4]);
            half4_t bf[4];
            #pragma unroll
            for (int t = 0; t < 4; ++t) {
                const int ry = (t >> 1) + ky;
                const int xx = (t & 1) * 16 + lq + kx;
                const int cichunk = sub * 4 + g;
                bf[t] = *reinterpret_cast<const half4_t*>(
                    &xs[(ry * 34 + xx) * 64 + ((cichunk ^ (xx & 15)) << 2)]);
            }
            #pragma unroll
            for (int cc = 0; cc < 3; ++cc)
                #pragma unroll
                for (int t = 0; t < 4; ++t)
                    acc[cc][t] = __builtin_amdgcn_mfma_f32_16x16x16f16(
                        af[cc], bf[t], acc[cc][t], 0, 0, 0);
        }
    }

    const float* bi = (s == 0) ? b1 : (s == 1) ? b2 : b12;
    _Float16* outb = qkv + (size_t)sb * CQKV * HW;
    #pragma unroll
    for (int cc = 0; cc < 3; ++cc) {
        const int ct = w * 3 + cc;
        const float bsc = (ct < 4) ? 0.25f : 1.f;
        const f32x4 bv4 = *reinterpret_cast<const f32x4*>(&bi[ct * 16 + g * 4]);
        #pragma unroll
        for (int t = 0; t < 4; ++t) {
            const int px = strip * 64 + t * 16 + lq;
            #pragma unroll
            for (int r = 0; r < 4; ++r) {
                const int ch = ct * 16 + g * 4 + r;
                outb[(size_t)ch * HW + px] = (_Float16)(acc[cc][t][r] + bsc * bv4[r]);
            }
        }
    }
}

// ---------------------------------------------------------------------------
// Kernel 2: rel-logit precompute, pre-shifted per query.
// qrel_t[bh][i][c]    = q1[i]·relw[c + 31 - x1]   (c = 0..31, x1 = i&31)
// qrel_t[bh][i][32+c] = q1[i]·relh[c + 31 - y1]   (y1 = i>>5)
// grid (4 islices, 32 bh), block 256, 1 query per thread; 128B/row writes.
// ---------------------------------------------------------------------------
__global__ __launch_bounds__(256) void qrel_kernel(
    const _Float16* __restrict__ qkv,
    const float* __restrict__ relw, const float* __restrict__ relh,
    _Float16* __restrict__ qrel_t)
{
    __shared__ float rw_s[63 * 16], rh_s[63 * 16];
    const int bh = blockIdx.y;
    const int b  = bh >> 2, h = bh & 3;
    const int i  = blockIdx.x * 256 + threadIdx.x;

    for (int e = threadIdx.x; e < 1008; e += 256) {
        rw_s[e] = relw[e];
        rh_s[e] = relh[e];
    }
    __syncthreads();

    const _Float16* qb = qkv + ((size_t)b * CQKV + h * 16) * HW + i;
    f32x4 qv[4];
    #pragma unroll
    for (int d = 0; d < 16; ++d) qv[d >> 2][d & 3] = (float)qb[(size_t)d * HW];

    const int x1 = i & 31, y1 = i >> 5;
    _Float16 row[64];
    #pragma unroll
    for (int c = 0; c < 32; ++c) {
        const f32x4* wp = reinterpret_cast<const f32x4*>(&rw_s[(c + 31 - x1) * 16]);
        const f32x4* hp = reinterpret_cast<const f32x4*>(&rh_s[(c + 31 - y1) * 16]);
        float sw = 0.f, sh = 0.f;
        #pragma unroll
        for (int dq = 0; dq < 4; ++dq) {
            const f32x4 wv = wp[dq], hv = hp[dq], qq = qv[dq];
            #pragma unroll
            for (int e = 0; e < 4; ++e) {
                sw = fmaf(qq[e], wv[e], sw);
                sh = fmaf(qq[e], hv[e], sh);
            }
        }
        row[c]      = (_Float16)sw;
        row[32 + c] = (_Float16)sh;
    }

    _Float16* dst = qrel_t + ((size_t)bh * HW + i) * 64;
    #pragma unroll
    for (int u = 0; u < 8; ++u)
        *reinterpret_cast<half8_t*>(&dst[u * 8]) =
            *reinterpret_cast<const half8_t*>(&row[u * 8]);
}

// ---------------------------------------------------------------------------
// Kernel 3: MFMA flash attention (f16 qkv, preloaded pre-shifted rel rows,
// lsum via ones-MFMA, fully unrolled, defer-max).
// grid: 768 1-D blocks, S = bid%3 (mixes workload), rest -> (bh, qb);
// same-(S,bh) blocks id-stride 96 == 0 mod 8 -> same XCD L2.
// ---------------------------------------------------------------------------
__global__ __launch_bounds__(512, 4) void attn_mfma_kernel(
    const _Float16* __restrict__ qkv,
    const _Float16* __restrict__ qrel_t,
    float* __restrict__ o)
{
    __shared__ _Float16 kf_lds[16384];   // 32 KB: K fragments
    __shared__ _Float16 vf_lds[16384];   // 32 KB: V fragments

    const int bid = blockIdx.x;
    const int S    = bid % 3;
    const int rest = bid / 3;
    const int bh   = rest & 31;
    const int qb   = rest >> 5;
    const int b   = bh >> 2, hd = bh & 3;
    const int tid = threadIdx.x;
    const int w    = tid >> 6;           // wave 0..7
    const int lane = tid & 63;
    const int g    = lane >> 4;
    const int lq   = lane & 15;
    const size_t SS = (size_t)Bn * CQKV * HW;

    const _Float16* qsrc = qkv + S * SS + ((size_t)b * CQKV + hd * 16) * HW;
    const _Float16* vsrc = qkv + S * SS + ((size_t)b * CQKV + 128 + hd * 16) * HW;
    const _Float16* k1p;
    const _Float16* k2p;
    if (S == 2) {
        k1p = qkv + 0 * SS + ((size_t)b * CQKV + 64 + hd * 16) * HW;
        k2p = qkv + 1 * SS + ((size_t)b * CQKV + 64 + hd * 16) * HW;
    } else {
        k1p = qkv + 2 * SS + ((size_t)b * CQKV + 64 + hd * 16) * HW;
        k2p = k1p;
    }

    // ---- stage K,V fragments (f16 global -> f16 LDS) ----------------------
    #pragma unroll 4
    for (int it = 0; it < 8; ++it) {
        const int idx = it * 512 + tid;          // 0..4095
        const int kt  = idx >> 6, l = idx & 63;
        const int row = l & 15;
        const int d0  = (l >> 4) * 4;
        const int lofs = (kt >> 1) * 512 + l * 8 + (kt & 1) * 4;

        const int key = kt * 16 + row;
        half4_t kh;
        if (S == 2) {
            #pragma unroll
            for (int j = 0; j < 4; ++j)
                kh[j] = (_Float16)((float)k1p[(size_t)(d0 + j) * HW + key]
                                 - (float)k2p[(size_t)(d0 + j) * HW + key]);
        } else {
            #pragma unroll
            for (int j = 0; j < 4; ++j)
                kh[j] = k1p[(size_t)(d0 + j) * HW + key];
        }
        *reinterpret_cast<half4_t*>(&kf_lds[lofs]) = kh;

        *reinterpret_cast<half4_t*>(&vf_lds[lofs]) =
            *reinterpret_cast<const half4_t*>(&vsrc[(size_t)row * HW + kt * 16 + d0]);
    }

    // ---- per-lane Q fragment + preloaded pre-shifted rel rows -------------
    const int qb0 = qb * 128 + w * 16;
    const int i   = qb0 + lq;

    half4_t qf;
    #pragma unroll
    for (int j = 0; j < 4; ++j) qf[j] = qsrc[(size_t)(g * 4 + j) * HW + i];

    float rwc0[4], rwc1[4];
    half8_t qhr[4];
    if (S == 0) {
        const _Float16* rrow = qrel_t + ((size_t)bh * HW + i) * 64;
        const half4_t rw0 = *reinterpret_cast<const half4_t*>(&rrow[g * 4]);
        const half4_t rw1 = *reinterpret_cast<const half4_t*>(&rrow[16 + g * 4]);
        #pragma unroll
        for (int r = 0; r < 4; ++r) {
            rwc0[r] = (float)rw0[r];
            rwc1[r] = (float)rw1[r];
        }
        #pragma unroll
        for (int u = 0; u < 4; ++u)
            qhr[u] = *reinterpret_cast<const half8_t*>(&rrow[32 + u * 8]);
    }

    __syncthreads();

    f32x4 acc  = {0.f, 0.f, 0.f, 0.f};
    f32x4 accS = {0.f, 0.f, 0.f, 0.f};
    float m = -1e30f;
    const f32x4 zero4 = {0.f, 0.f, 0.f, 0.f};
    const half4_t onef = {(_Float16)1.f, (_Float16)1.f, (_Float16)1.f, (_Float16)1.f};

    // ---- online-softmax sweep: fully unrolled 16 iters x 64 keys ----------
    #pragma unroll
    for (int c = 0; c < 32; c += 2) {
        const half8_t kk0 = *reinterpret_cast<const half8_t*>(&kf_lds[c * 512 + lane * 8]);
        const half8_t kk1 = *reinterpret_cast<const half8_t*>(&kf_lds[(c + 1) * 512 + lane * 8]);
        const half8_t vv0 = *reinterpret_cast<const half8_t*>(&vf_lds[c * 512 + lane * 8]);
        const half8_t vv1 = *reinterpret_cast<const half8_t*>(&vf_lds[(c + 1) * 512 + lane * 8]);

        f32x4 s0 = __builtin_amdgcn_mfma_f32_16x16x16f16(
            __builtin_shufflevector(kk0, kk0, 0, 1, 2, 3), qf, zero4, 0, 0, 0);
        f32x4 s1 = __builtin_amdgcn_mfma_f32_16x16x16f16(
            __builtin_shufflevector(kk0, kk0, 4, 5, 6, 7), qf, zero4, 0, 0, 0);
        f32x4 s2 = __builtin_amdgcn_mfma_f32_16x16x16f16(
            __builtin_shufflevector(kk1, kk1, 0, 1, 2, 3), qf, zero4, 0, 0, 0);
        f32x4 s3 = __builtin_amdgcn_mfma_f32_16x16x16f16(
            __builtin_shufflevector(kk1, kk1, 4, 5, 6, 7), qf, zero4, 0, 0, 0);

        if (S == 0) {
            const float rh0 = (float)qhr[c >> 3][c & 7];
            const float rh1 = (float)qhr[(c + 1) >> 3][(c + 1) & 7];
            #pragma unroll
            for (int r = 0; r < 4; ++r) {
                s0[r] += rh0 + rwc0[r];
                s1[r] += rh0 + rwc1[r];
                s2[r] += rh1 + rwc0[r];
                s3[r] += rh1 + rwc1[r];
            }
        }

        float a0 = fmaxf(fmaxf(s0[0], s0[1]), s0[2]);
        float a1 = fmaxf(fmaxf(s0[3], s1[0]), s1[1]);
        float a2 = fmaxf(fmaxf(s1[2], s1[3]), s2[0]);
        float a3 = fmaxf(fmaxf(s2[1], s2[2]), s2[3]);
        float a4 = fmaxf(fmaxf(s3[0], s3[1]), s3[2]);
        float vmax = fmaxf(fmaxf(fmaxf(a0, a1), fmaxf(a2, a3)),
                           fmaxf(a4, s3[3]));

        if (!__all(vmax <= m + 8.f)) {
            float wmax = fmaxf(vmax, __shfl_xor(vmax, 16));
            wmax = fmaxf(wmax, __shfl_xor(wmax, 32));
            const float mnew = fmaxf(m, wmax);
            const float fsc  = __expf(m - mnew);
            m = mnew;
            acc  *= fsc;
            accS *= fsc;
        }

        half4_t pa, pb, pc, pd;
        #pragma unroll
        for (int r = 0; r < 4; ++r) {
            pa[r] = (_Float16)__expf(s0[r] - m);
            pb[r] = (_Float16)__expf(s1[r] - m);
            pc[r] = (_Float16)__expf(s2[r] - m);
            pd[r] = (_Float16)__expf(s3[r] - m);
        }

        acc = __builtin_amdgcn_mfma_f32_16x16x16f16(
            __builtin_shufflevector(vv0, vv0, 0, 1, 2, 3), pa, acc, 0, 0, 0);
        acc = __builtin_amdgcn_mfma_f32_16x16x16f16(
            __builtin_shufflevector(vv0, vv0, 4, 5, 6, 7), pb, acc, 0, 0, 0);
        acc = __builtin_amdgcn_mfma_f32_16x16x16f16(
            __builtin_shufflevector(vv1, vv1, 0, 1, 2, 3), pc, acc, 0, 0, 0);
        acc = __builtin_amdgcn_mfma_f32_16x16x16f16(
            __builtin_shufflevector(vv1, vv1, 4, 5, 6, 7), pd, acc, 0, 0, 0);

        accS = __builtin_amdgcn_mfma_f32_16x16x16f16(onef, pa, accS, 0, 0, 0);
        accS = __builtin_amdgcn_mfma_f32_16x16x16f16(onef, pb, accS, 0, 0, 0);
        accS = __builtin_amdgcn_mfma_f32_16x16x16f16(onef, pc, accS, 0, 0, 0);
        accS = __builtin_amdgcn_mfma_f32_16x16x16f16(onef, pd, accS, 0, 0, 0);
    }

    const float inv = 1.f / accS[0];

    float* op = o + ((((size_t)S * Bn + b) * NHh + hd) * HW) * 16;
    f32x4 res;
    #pragma unroll
    for (int r = 0; r < 4; ++r) res[r] = acc[r] * inv;
    *reinterpret_cast<f32x4*>(&op[(size_t)i * 16 + g * 4]) = res;
}

// ---------------------------------------------------------------------------
// Kernel 4: 1x1 output conv (unchanged; o stays f32).
// ---------------------------------------------------------------------------
__global__ __launch_bounds__(256) void out_conv_kernel(
    const float* __restrict__ o, const float* __restrict__ wout,
    const float* __restrict__ bout, float* __restrict__ out)
{
    const int co = blockIdx.x;
    const int sb = blockIdx.y;
    const int tid = threadIdx.x;
    const float* ob = o + (size_t)sb * 64 * HW;

    float acc[4] = {0.f, 0.f, 0.f, 0.f};
    for (int c = 0; c < 64; ++c) {
        const float wv = wout[co * 64 + c];
        #pragma unroll
        for (int p = 0; p < 4; ++p)
            acc[p] = fmaf(wv, ob[(size_t)c * HW + tid + p * 256], acc[p]);
    }
    const float bv = bout[co];
    #pragma unroll
    for (int p = 0; p < 4; ++p)
        out[((size_t)sb * 64 + co) * HW + tid + p * 256] = acc[p] + bv;
}

// ---------------------------------------------------------------------------
extern "C" void kernel_launch(void* const* d_in, const int* in_sizes, int n_in,
                              void* d_out, int out_size, void* d_ws, size_t ws_size,
                              hipStream_t stream)
{
    const float* x1   = (const float*)d_in[0];
    const float* x2   = (const float*)d_in[1];
    const float* x12  = (const float*)d_in[2];
    const float* wq1  = (const float*)d_in[3];
    const float* bq1  = (const float*)d_in[4];
    const float* wq2  = (const float*)d_in[5];
    const float* bq2  = (const float*)d_in[6];
    const float* wq12 = (const float*)d_in[7];
    const float* bq12 = (const float*)d_in[8];
    const float* wout = (const float*)d_in[9];
    const float* bout = (const float*)d_in[10];
    const float* relw = (const float*)d_in[11];
    const float* relh = (const float*)d_in[12];

    // workspace layout (no aliasing): qkv16 9MB | o 6MB | qrel_t 4MB | xt | wf
    _Float16* qkv16  = (_Float16*)d_ws;                       // 4,718,592 h
    float*    o      = (float*)(qkv16 + (size_t)4718592);     // 1,572,864 f
    _Float16* qrel_t = (_Float16*)(o + (size_t)1572864);      // 2,097,152 h
    _Float16* xt     = qrel_t + (size_t)2097152;              // 1,775,616 h
    _Float16* wf     = xt + (size_t)1775616;                  //   331,776 h

    prep_xt_kernel<<<dim3(24, 8), 256, 0, stream>>>(x1, x2, x12, xt);
    prep_wf_kernel<<<dim3(324), 256, 0, stream>>>(wq1, wq2, wq12, wf);

    conv_mfma_kernel<<<dim3(16, 8, 3), 256, 0, stream>>>(
        xt, wf, bq1, bq2, bq12, qkv16);

    qrel_kernel<<<dim3(4, 32), 256, 0, stream>>>(qkv16, relw, relh, qrel_t);

    attn_mfma_kernel<<<dim3(768), 512, 0, stream>>>(qkv16, qrel_t, o);

    out_conv_kernel<<<dim3(64, 24), 256, 0, stream>>>(o, wout, bout, (float*)d_out);
}

// Round 11
// 76.355 us; speedup vs baseline: 2.9466x; 1.1989x over previous
//
#include <hip/hip_runtime.h>
#include <math.h>

#define Bn 8
#define CIN 64
#define HH 32
#define WW 32
#define HW 1024
#define CQKV 192
#define NHh 4
#define DKHd 16
#define DVHd 16
#define QSCALE 0.36067376f   // 0.25 * log2(e): whole softmax lives in exp2 domain

typedef _Float16 half4_t __attribute__((ext_vector_type(4)));
typedef _Float16 half8_t __attribute__((ext_vector_type(8)));
typedef __fp16 fp16x2_t __attribute__((ext_vector_type(2)));
typedef __fp16 fp16x4_t __attribute__((ext_vector_type(4)));
typedef float f32x4 __attribute__((ext_vector_type(4)));

#if __has_builtin(__builtin_amdgcn_exp2f)
#define EXP2F(x) __builtin_amdgcn_exp2f(x)
#else
#define EXP2F(x) exp2f(x)
#endif

static __device__ __forceinline__ half4_t pack4(float a, float b, float c, float d)
{
#if __has_builtin(__builtin_amdgcn_cvt_pkrtz)
    fp16x2_t lo = __builtin_amdgcn_cvt_pkrtz(a, b);
    fp16x2_t hi = __builtin_amdgcn_cvt_pkrtz(c, d);
    fp16x4_t v4 = __builtin_shufflevector(lo, hi, 0, 1, 2, 3);
    return __builtin_bit_cast(half4_t, v4);
#else
    half4_t r;
    r[0] = (_Float16)a; r[1] = (_Float16)b; r[2] = (_Float16)c; r[3] = (_Float16)d;
    return r;
#endif
}

// ---------------------------------------------------------------------------
// Prep A: x (f32, [sb][ci][32][32]) -> xt (f16, [sb][34][34][64]) zero-padded.
// ---------------------------------------------------------------------------
__global__ __launch_bounds__(256) void prep_xt_kernel(
    const float* __restrict__ x1, const float* __restrict__ x2,
    const float* __restrict__ x12, _Float16* __restrict__ xt)
{
    const int sb = blockIdx.x;           // s*8 + b
    const int s  = sb >> 3, b = sb & 7;
    const int ci0 = blockIdx.y * 8;
    const float* x = (s == 0) ? x1 : (s == 1) ? x2 : x12;
    const float* xb = x + (size_t)b * CIN * HW;

    for (int pos = threadIdx.x; pos < 34 * 34; pos += 256) {
        const int row = pos / 34, col = pos % 34;
        const int gy = row - 1, gx = col - 1;
        half8_t v;
        if ((unsigned)gy < 32u && (unsigned)gx < 32u) {
            #pragma unroll
            for (int j = 0; j < 8; ++j)
                v[j] = (_Float16)xb[(size_t)(ci0 + j) * HW + gy * 32 + gx];
        } else {
            #pragma unroll
            for (int j = 0; j < 8; ++j) v[j] = (_Float16)0.f;
        }
        *reinterpret_cast<half8_t*>(&xt[((size_t)sb * 1156 + pos) * 64 + ci0]) = v;
    }
}

// ---------------------------------------------------------------------------
// Prep B: weights -> A-fragment layout wf[s][ct(12)][ks(36)][lane(64)][4] f16.
// q channels scaled by 0.25*log2e.
// ---------------------------------------------------------------------------
__global__ __launch_bounds__(256) void prep_wf_kernel(
    const float* __restrict__ w1, const float* __restrict__ w2,
    const float* __restrict__ w12, _Float16* __restrict__ wf)
{
    const int f = blockIdx.x * 256 + threadIdx.x;   // 82944 frags
    if (f >= 3 * 12 * 36 * 64) return;
    const int lane = f & 63;
    int r = f >> 6;
    const int ks = r % 36; r /= 36;
    const int ct = r % 12; const int s = r / 12;
    const float* w = (s == 0) ? w1 : (s == 1) ? w2 : w12;

    const int tap = ks >> 2;
    const int ci_b = (ks & 3) * 16 + (lane >> 4) * 4;
    const int co = ct * 16 + (lane & 15);
    const float scale = (co < 64) ? QSCALE : 1.f;

    half4_t v;
    #pragma unroll
    for (int j = 0; j < 4; ++j)
        v[j] = (_Float16)(w[((size_t)co * 64 + ci_b + j) * 9 + tap] * scale);
    *reinterpret_cast<half4_t*>(&wf[(size_t)f * 4]) = v;
}

// ---------------------------------------------------------------------------
// Kernel 1: implicit-GEMM 3x3 conv via MFMA. Output f16.
// ---------------------------------------------------------------------------
__global__ __launch_bounds__(256) void conv_mfma_kernel(
    const _Float16* __restrict__ xt, const _Float16* __restrict__ wf,
    const float* __restrict__ b1, const float* __restrict__ b2,
    const float* __restrict__ b12, _Float16* __restrict__ qkv)
{
    __shared__ _Float16 xs[8704];        // 4*34*64
    const int strip = blockIdx.x;
    const int b = blockIdx.y, s = blockIdx.z;
    const int sb = s * Bn + b;
    const int tid = threadIdx.x;
    const int w = tid >> 6, lane = tid & 63, g = lane >> 4, lq = lane & 15;
    const int y0 = strip * 2;

    const half4_t* src = reinterpret_cast<const half4_t*>(
        xt + ((size_t)sb * 1156 + y0 * 34) * 64);
    for (int c = tid; c < 2176; c += 256) {
        const int cic = c & 15;
        const int colrow = c >> 4;
        const int xx = colrow % 34;
        const int lofs = colrow * 64 + ((cic ^ (xx & 15)) << 2);
        *reinterpret_cast<half4_t*>(&xs[lofs]) = src[c];
    }
    __syncthreads();

    f32x4 acc[3][4];
    #pragma unroll
    for (int cc = 0; cc < 3; ++cc)
        #pragma unroll
        for (int t = 0; t < 4; ++t) acc[cc][t] = (f32x4){0.f, 0.f, 0.f, 0.f};

    const _Float16* wfs = wf + ((size_t)(s * 12 + w * 3) * 36) * 256;

    #pragma unroll
    for (int tap = 0; tap < 9; ++tap) {
        const int ky = tap / 3, kx = tap % 3;
        #pragma unroll
        for (int sub = 0; sub < 4; ++sub) {
            const int ks = tap * 4 + sub;
            half4_t af[3];
            #pragma unroll
            for (int cc = 0; cc < 3; ++cc)
                af[cc] = *reinterpret_cast<const half4_t*>(
                    &wfs[((size_t)cc * 36 + ks) * 256 + lane * 4]);
            half4_t bf[4];
            #pragma unroll
            for (int t = 0; t < 4; ++t) {
                const int ry = (t >> 1) + ky;
                const int xx = (t & 1) * 16 + lq + kx;
                const int cichunk = sub * 4 + g;
                bf[t] = *reinterpret_cast<const half4_t*>(
                    &xs[(ry * 34 + xx) * 64 + ((cichunk ^ (xx & 15)) << 2)]);
            }
            #pragma unroll
            for (int cc = 0; cc < 3; ++cc)
                #pragma unroll
                for (int t = 0; t < 4; ++t)
                    acc[cc][t] = __builtin_amdgcn_mfma_f32_16x16x16f16(
                        af[cc], bf[t], acc[cc][t], 0, 0, 0);
        }
    }

    const float* bi = (s == 0) ? b1 : (s == 1) ? b2 : b12;
    _Float16* outb = qkv + (size_t)sb * CQKV * HW;
    #pragma unroll
    for (int cc = 0; cc < 3; ++cc) {
        const int ct = w * 3 + cc;
        const float bsc = (ct < 4) ? QSCALE : 1.f;
        const f32x4 bv4 = *reinterpret_cast<const f32x4*>(&bi[ct * 16 + g * 4]);
        #pragma unroll
        for (int t = 0; t < 4; ++t) {
            const int px = strip * 64 + t * 16 + lq;
            #pragma unroll
            for (int r = 0; r < 4; ++r) {
                const int ch = ct * 16 + g * 4 + r;
                outb[(size_t)ch * HW + px] = (_Float16)(acc[cc][t][r] + bsc * bv4[r]);
            }
        }
    }
}

// ---------------------------------------------------------------------------
// Kernel 2: rel-logit precompute, pre-shifted per query.
// ---------------------------------------------------------------------------
__global__ __launch_bounds__(256) void qrel_kernel(
    const _Float16* __restrict__ qkv,
    const float* __restrict__ relw, const float* __restrict__ relh,
    _Float16* __restrict__ qrel_t)
{
    __shared__ float rw_s[63 * 16], rh_s[63 * 16];
    const int bh = blockIdx.y;
    const int b  = bh >> 2, h = bh & 3;
    const int i  = blockIdx.x * 256 + threadIdx.x;

    for (int e = threadIdx.x; e < 1008; e += 256) {
        rw_s[e] = relw[e];
        rh_s[e] = relh[e];
    }
    __syncthreads();

    const _Float16* qb = qkv + ((size_t)b * CQKV + h * 16) * HW + i;
    f32x4 qv[4];
    #pragma unroll
    for (int d = 0; d < 16; ++d) qv[d >> 2][d & 3] = (float)qb[(size_t)d * HW];

    const int x1 = i & 31, y1 = i >> 5;
    _Float16 row[64];
    #pragma unroll
    for (int c = 0; c < 32; ++c) {
        const f32x4* wp = reinterpret_cast<const f32x4*>(&rw_s[(c + 31 - x1) * 16]);
        const f32x4* hp = reinterpret_cast<const f32x4*>(&rh_s[(c + 31 - y1) * 16]);
        float sw = 0.f, sh = 0.f;
        #pragma unroll
        for (int dq = 0; dq < 4; ++dq) {
            const f32x4 wv = wp[dq], hv = hp[dq], qq = qv[dq];
            #pragma unroll
            for (int e = 0; e < 4; ++e) {
                sw = fmaf(qq[e], wv[e], sw);
                sh = fmaf(qq[e], hv[e], sh);
            }
        }
        row[c]      = (_Float16)sw;
        row[32 + c] = (_Float16)sh;
    }

    _Float16* dst = qrel_t + ((size_t)bh * HW + i) * 64;
    #pragma unroll
    for (int u = 0; u < 8; ++u)
        *reinterpret_cast<half8_t*>(&dst[u * 8]) =
            *reinterpret_cast<const half8_t*>(&row[u * 8]);
}

// ---------------------------------------------------------------------------
// Kernel 3: MFMA flash attention (exp2 domain; rel-w as MFMA C-operand;
// rel-h folded into the subtracted max; pkrtz P packing).
// o16 written f16 in the r7-verified FLAT layout [sb][hd][i*16+dv]: the
// reference's raw (HW,DVH)->(DVH,H,W) reshape means conv channel c at px is
// flat element c*1024+px of this buffer (faithful garble) — do NOT "fix" it.
// ---------------------------------------------------------------------------
__global__ __launch_bounds__(512, 4) void attn_mfma_kernel(
    const _Float16* __restrict__ qkv,
    const _Float16* __restrict__ qrel_t,
    _Float16* __restrict__ o16)
{
    __shared__ _Float16 kf_lds[16384];   // 32 KB: K fragments
    __shared__ _Float16 vf_lds[16384];   // 32 KB: V fragments

    const int bid = blockIdx.x;
    const int S    = bid % 3;
    const int rest = bid / 3;
    const int bh   = rest & 31;
    const int qb   = rest >> 5;
    const int b   = bh >> 2, hd = bh & 3;
    const int tid = threadIdx.x;
    const int w    = tid >> 6;           // wave 0..7
    const int lane = tid & 63;
    const int g    = lane >> 4;
    const int lq   = lane & 15;
    const size_t SS = (size_t)Bn * CQKV * HW;

    const _Float16* qsrc = qkv + S * SS + ((size_t)b * CQKV + hd * 16) * HW;
    const _Float16* vsrc = qkv + S * SS + ((size_t)b * CQKV + 128 + hd * 16) * HW;
    const _Float16* k1p;
    const _Float16* k2p;
    if (S == 2) {
        k1p = qkv + 0 * SS + ((size_t)b * CQKV + 64 + hd * 16) * HW;
        k2p = qkv + 1 * SS + ((size_t)b * CQKV + 64 + hd * 16) * HW;
    } else {
        k1p = qkv + 2 * SS + ((size_t)b * CQKV + 64 + hd * 16) * HW;
        k2p = k1p;
    }

    // ---- stage K,V fragments (f16 global -> f16 LDS) ----------------------
    #pragma unroll 4
    for (int it = 0; it < 8; ++it) {
        const int idx = it * 512 + tid;          // 0..4095
        const int kt  = idx >> 6, l = idx & 63;
        const int row = l & 15;
        const int d0  = (l >> 4) * 4;
        const int lofs = (kt >> 1) * 512 + l * 8 + (kt & 1) * 4;

        const int key = kt * 16 + row;
        half4_t kh;
        if (S == 2) {
            #pragma unroll
            for (int j = 0; j < 4; ++j)
                kh[j] = (_Float16)((float)k1p[(size_t)(d0 + j) * HW + key]
                                 - (float)k2p[(size_t)(d0 + j) * HW + key]);
        } else {
            #pragma unroll
            for (int j = 0; j < 4; ++j)
                kh[j] = k1p[(size_t)(d0 + j) * HW + key];
        }
        *reinterpret_cast<half4_t*>(&kf_lds[lofs]) = kh;

        *reinterpret_cast<half4_t*>(&vf_lds[lofs]) =
            *reinterpret_cast<const half4_t*>(&vsrc[(size_t)row * HW + kt * 16 + d0]);
    }

    // ---- per-lane Q fragment + preloaded pre-shifted rel rows -------------
    const int qb0 = qb * 128 + w * 16;
    const int i   = qb0 + lq;

    half4_t qf;
    #pragma unroll
    for (int j = 0; j < 4; ++j) qf[j] = qsrc[(size_t)(g * 4 + j) * HW + i];

    f32x4 crw0 = {0.f, 0.f, 0.f, 0.f}, crw1 = {0.f, 0.f, 0.f, 0.f};
    half8_t qhr[4];
    if (S == 0) {
        const _Float16* rrow = qrel_t + ((size_t)bh * HW + i) * 64;
        const half4_t rw0 = *reinterpret_cast<const half4_t*>(&rrow[g * 4]);
        const half4_t rw1 = *reinterpret_cast<const half4_t*>(&rrow[16 + g * 4]);
        #pragma unroll
        for (int r = 0; r < 4; ++r) {
            crw0[r] = (float)rw0[r];
            crw1[r] = (float)rw1[r];
        }
        #pragma unroll
        for (int u = 0; u < 4; ++u)
            qhr[u] = *reinterpret_cast<const half8_t*>(&rrow[32 + u * 8]);
    } else {
        #pragma unroll
        for (int u = 0; u < 4; ++u)
            qhr[u] = (half8_t)(_Float16)0.f;
    }

    __syncthreads();

    f32x4 acc  = {0.f, 0.f, 0.f, 0.f};
    f32x4 accS = {0.f, 0.f, 0.f, 0.f};
    float m = -1e30f;
    const half4_t onef = {(_Float16)1.f, (_Float16)1.f, (_Float16)1.f, (_Float16)1.f};

    // ---- online-softmax sweep: fully unrolled 16 iters x 64 keys ----------
    #pragma unroll
    for (int c = 0; c < 32; c += 2) {
        const half8_t kk0 = *reinterpret_cast<const half8_t*>(&kf_lds[c * 512 + lane * 8]);
        const half8_t kk1 = *reinterpret_cast<const half8_t*>(&kf_lds[(c + 1) * 512 + lane * 8]);
        const half8_t vv0 = *reinterpret_cast<const half8_t*>(&vf_lds[c * 512 + lane * 8]);
        const half8_t vv1 = *reinterpret_cast<const half8_t*>(&vf_lds[(c + 1) * 512 + lane * 8]);

        const float rh0 = (float)qhr[c >> 3][c & 7];
        const float rh1 = (float)qhr[(c + 1) >> 3][(c + 1) & 7];

        // rel-w rides in on the C-operand (free add on the matrix pipe)
        f32x4 s0 = __builtin_amdgcn_mfma_f32_16x16x16f16(
            __builtin_shufflevector(kk0, kk0, 0, 1, 2, 3), qf, crw0, 0, 0, 0);
        f32x4 s1 = __builtin_amdgcn_mfma_f32_16x16x16f16(
            __builtin_shufflevector(kk0, kk0, 4, 5, 6, 7), qf, crw1, 0, 0, 0);
        f32x4 s2 = __builtin_amdgcn_mfma_f32_16x16x16f16(
            __builtin_shufflevector(kk1, kk1, 0, 1, 2, 3), qf, crw0, 0, 0, 0);
        f32x4 s3 = __builtin_amdgcn_mfma_f32_16x16x16f16(
            __builtin_shufflevector(kk1, kk1, 4, 5, 6, 7), qf, crw1, 0, 0, 0);

        float a0 = fmaxf(fmaxf(s0[0], s0[1]), fmaxf(s0[2], s0[3]));
        float a1 = fmaxf(fmaxf(s1[0], s1[1]), fmaxf(s1[2], s1[3]));
        float a2 = fmaxf(fmaxf(s2[0], s2[1]), fmaxf(s2[2], s2[3]));
        float a3 = fmaxf(fmaxf(s3[0], s3[1]), fmaxf(s3[2], s3[3]));
        // true score = s + rh  (rh uniform across the rows of each key-row)
        const float vmax = fmaxf(fmaxf(a0, a1) + rh0, fmaxf(a2, a3) + rh1);

        // defer-max: threshold 8 nats = 11.53 bits
        if (!__all(vmax <= m + 11.53f)) {
            float wmax = fmaxf(vmax, __shfl_xor(vmax, 16));
            wmax = fmaxf(wmax, __shfl_xor(wmax, 32));
            const float mnew = fmaxf(m, wmax);
            const float fsc  = EXP2F(m - mnew);
            m = mnew;
            acc  *= fsc;
            accS *= fsc;
        }

        // rel-h folds into the subtracted max
        const float mm0 = m - rh0;
        const float mm1 = m - rh1;

        const half4_t pa = pack4(EXP2F(s0[0] - mm0), EXP2F(s0[1] - mm0),
                                 EXP2F(s0[2] - mm0), EXP2F(s0[3] - mm0));
        const half4_t pb = pack4(EXP2F(s1[0] - mm0), EXP2F(s1[1] - mm0),
                                 EXP2F(s1[2] - mm0), EXP2F(s1[3] - mm0));
        const half4_t pc = pack4(EXP2F(s2[0] - mm1), EXP2F(s2[1] - mm1),
                                 EXP2F(s2[2] - mm1), EXP2F(s2[3] - mm1));
        const half4_t pd = pack4(EXP2F(s3[0] - mm1), EXP2F(s3[1] - mm1),
                                 EXP2F(s3[2] - mm1), EXP2F(s3[3] - mm1));

        acc = __builtin_amdgcn_mfma_f32_16x16x16f16(
            __builtin_shufflevector(vv0, vv0, 0, 1, 2, 3), pa, acc, 0, 0, 0);
        acc = __builtin_amdgcn_mfma_f32_16x16x16f16(
            __builtin_shufflevector(vv0, vv0, 4, 5, 6, 7), pb, acc, 0, 0, 0);
        acc = __builtin_amdgcn_mfma_f32_16x16x16f16(
            __builtin_shufflevector(vv1, vv1, 0, 1, 2, 3), pc, acc, 0, 0, 0);
        acc = __builtin_amdgcn_mfma_f32_16x16x16f16(
            __builtin_shufflevector(vv1, vv1, 4, 5, 6, 7), pd, acc, 0, 0, 0);

        accS = __builtin_amdgcn_mfma_f32_16x16x16f16(onef, pa, accS, 0, 0, 0);
        accS = __builtin_amdgcn_mfma_f32_16x16x16f16(onef, pb, accS, 0, 0, 0);
        accS = __builtin_amdgcn_mfma_f32_16x16x16f16(onef, pc, accS, 0, 0, 0);
        accS = __builtin_amdgcn_mfma_f32_16x16x16f16(onef, pd, accS, 0, 0, 0);
    }

    const float inv = 1.f / accS[0];

    // FLAT r7 layout: o16[sb][hd][i*16 + dv], dv = g*4 + r  (contiguous half4)
    _Float16* op = o16 + (size_t)(S * Bn + b) * 65536 + (size_t)hd * 16384
                 + (size_t)i * 16 + g * 4;
    *reinterpret_cast<half4_t*>(op) =
        pack4(acc[0] * inv, acc[1] * inv, acc[2] * inv, acc[3] * inv);
}

// ---------------------------------------------------------------------------
// Kernel 4: 1x1 output conv via MFMA, faithful to the reference's raw reshape:
// conv input channel c at pixel px = o16[sb*65536 + c*1024 + px]  (V[c][px]).
// Stage V-strip TRANSPOSED into LDS ([t][c], chunk-XOR swizzled) so B-frags
// are contiguous conflict-free half4 reads. A-side (wout) as before.
// grid (16 px-strips, 24 sb), block 256 = 4 waves; wave w -> co-tile w.
// ---------------------------------------------------------------------------
__global__ __launch_bounds__(256) void out_conv_mfma_kernel(
    const _Float16* __restrict__ o16, const float* __restrict__ wout,
    const float* __restrict__ bout, float* __restrict__ out)
{
    __shared__ _Float16 wls[4096];   // w[co][ci], chunk c>>2 stored at ^co&15
    __shared__ _Float16 ols[4096];   // V^T[t][c], chunk c>>2 stored at ^t&15
    const int strip = blockIdx.x;
    const int sb    = blockIdx.y;
    const int tid = threadIdx.x;
    const int w = tid >> 6, lane = tid & 63, g = lane >> 4, lq = lane & 15;

    // ---- stage wout (f32->f16, swizzled) -----------------------------------
    {
        const int row = tid >> 2;            // co 0..63
        const int cg  = (tid & 3) * 4;       // chunk group base
        #pragma unroll
        for (int k = 0; k < 4; ++k) {
            const int c = cg + k;            // chunk 0..15 (4 halfs each)
            const f32x4 wv = *reinterpret_cast<const f32x4*>(&wout[(row * 16 + c) * 4]);
            *reinterpret_cast<half4_t*>(&wls[row * 64 + ((c ^ (row & 15)) << 2)]) =
                pack4(wv[0], wv[1], wv[2], wv[3]);
        }
    }
    // ---- stage V-strip transposed: ols[t][c] = V[c][strip*64 + t] ----------
    {
        const _Float16* osrc = o16 + (size_t)sb * 65536 + strip * 64;
        #pragma unroll
        for (int it = 0; it < 2; ++it) {
            const int idx = it * 256 + tid;      // 0..511
            const int c   = idx >> 3;            // channel 0..63
            const int t0  = (idx & 7) * 8;       // px-local base
            const half8_t v = *reinterpret_cast<const half8_t*>(
                &osrc[(size_t)c * HW + t0]);
            #pragma unroll
            for (int e = 0; e < 8; ++e) {
                const int t = t0 + e;
                ols[t * 64 + ((((c >> 2) ^ (t & 15)) << 2) + (c & 3))] = v[e];
            }
        }
    }
    __syncthreads();

    // ---- A fragments: w[co = w*16+lq][ci = ks*16 + g*4 + j] ----------------
    half4_t af[4];
    #pragma unroll
    for (int ks = 0; ks < 4; ++ks)
        af[ks] = *reinterpret_cast<const half4_t*>(
            &wls[(w * 16 + lq) * 64 + (((ks * 4 + g) ^ lq) << 2)]);

    const f32x4 bv4 = *reinterpret_cast<const f32x4*>(&bout[w * 16 + g * 4]);

    #pragma unroll
    for (int pt = 0; pt < 4; ++pt) {
        f32x4 acc = {0.f, 0.f, 0.f, 0.f};
        #pragma unroll
        for (int ks = 0; ks < 4; ++ks) {
            // B[k = ci-local][n = t]: ols[t][ci = ks*16 + g*4 + j]
            const half4_t bf = *reinterpret_cast<const half4_t*>(
                &ols[(pt * 16 + lq) * 64 + (((ks * 4 + g) ^ lq) << 2)]);
            acc = __builtin_amdgcn_mfma_f32_16x16x16f16(af[ks], bf, acc, 0, 0, 0);
        }
        const int px = strip * 64 + pt * 16 + lq;
        #pragma unroll
        for (int r = 0; r < 4; ++r) {
            const int co = w * 16 + g * 4 + r;
            out[((size_t)sb * 64 + co) * HW + px] = acc[r] + bv4[r];
        }
    }
}

// ---------------------------------------------------------------------------
extern "C" void kernel_launch(void* const* d_in, const int* in_sizes, int n_in,
                              void* d_out, int out_size, void* d_ws, size_t ws_size,
                              hipStream_t stream)
{
    const float* x1   = (const float*)d_in[0];
    const float* x2   = (const float*)d_in[1];
    const float* x12  = (const float*)d_in[2];
    const float* wq1  = (const float*)d_in[3];
    const float* bq1  = (const float*)d_in[4];
    const float* wq2  = (const float*)d_in[5];
    const float* bq2  = (const float*)d_in[6];
    const float* wq12 = (const float*)d_in[7];
    const float* bq12 = (const float*)d_in[8];
    const float* wout = (const float*)d_in[9];
    const float* bout = (const float*)d_in[10];
    const float* relw = (const float*)d_in[11];
    const float* relh = (const float*)d_in[12];

    // workspace: qkv16 | o16 | qrel_t | xt | wf  (all f16, ~21 MB)
    _Float16* qkv16  = (_Float16*)d_ws;                       // 4,718,592 h
    _Float16* o16    = qkv16 + (size_t)4718592;               // 1,572,864 h
    _Float16* qrel_t = o16 + (size_t)1572864;                 // 2,097,152 h
    _Float16* xt     = qrel_t + (size_t)2097152;              // 1,775,616 h
    _Float16* wf     = xt + (size_t)1775616;                  //   331,776 h

    prep_xt_kernel<<<dim3(24, 8), 256, 0, stream>>>(x1, x2, x12, xt);
    prep_wf_kernel<<<dim3(324), 256, 0, stream>>>(wq1, wq2, wq12, wf);

    conv_mfma_kernel<<<dim3(16, 8, 3), 256, 0, stream>>>(
        xt, wf, bq1, bq2, bq12, qkv16);

    qrel_kernel<<<dim3(4, 32), 256, 0, stream>>>(qkv16, relw, relh, qrel_t);

    attn_mfma_kernel<<<dim3(768), 512, 0, stream>>>(qkv16, qrel_t, o16);

    out_conv_mfma_kernel<<<dim3(16, 24), 256, 0, stream>>>(
        o16, wout, bout, (float*)d_out);
}

// Round 12
// 72.629 us; speedup vs baseline: 3.0977x; 1.0513x over previous
//
#include <hip/hip_runtime.h>
#include <math.h>

#define Bn 8
#define CIN 64
#define HH 32
#define WW 32
#define HW 1024
#define CQKV 192
#define NHh 4
#define DKHd 16
#define DVHd 16
#define QSCALE 0.36067376f   // 0.25 * log2(e): whole softmax lives in exp2 domain

typedef _Float16 half4_t __attribute__((ext_vector_type(4)));
typedef _Float16 half8_t __attribute__((ext_vector_type(8)));
typedef __fp16 fp16x2_t __attribute__((ext_vector_type(2)));
typedef __fp16 fp16x4_t __attribute__((ext_vector_type(4)));
typedef float f32x4 __attribute__((ext_vector_type(4)));

#if __has_builtin(__builtin_amdgcn_exp2f)
#define EXP2F(x) __builtin_amdgcn_exp2f(x)
#else
#define EXP2F(x) exp2f(x)
#endif

static __device__ __forceinline__ half4_t pack4(float a, float b, float c, float d)
{
#if __has_builtin(__builtin_amdgcn_cvt_pkrtz)
    fp16x2_t lo = __builtin_amdgcn_cvt_pkrtz(a, b);
    fp16x2_t hi = __builtin_amdgcn_cvt_pkrtz(c, d);
    fp16x4_t v4 = __builtin_shufflevector(lo, hi, 0, 1, 2, 3);
    return __builtin_bit_cast(half4_t, v4);
#else
    half4_t r;
    r[0] = (_Float16)a; r[1] = (_Float16)b; r[2] = (_Float16)c; r[3] = (_Float16)d;
    return r;
#endif
}

// ---------------------------------------------------------------------------
// Prep B: weights -> A-fragment layout wf[s][ct(12)][ks(36)][lane(64)][4] f16.
// q channels scaled by 0.25*log2e.
// ---------------------------------------------------------------------------
__global__ __launch_bounds__(256) void prep_wf_kernel(
    const float* __restrict__ w1, const float* __restrict__ w2,
    const float* __restrict__ w12, _Float16* __restrict__ wf)
{
    const int f = blockIdx.x * 256 + threadIdx.x;   // 82944 frags
    if (f >= 3 * 12 * 36 * 64) return;
    const int lane = f & 63;
    int r = f >> 6;
    const int ks = r % 36; r /= 36;
    const int ct = r % 12; const int s = r / 12;
    const float* w = (s == 0) ? w1 : (s == 1) ? w2 : w12;

    const int tap = ks >> 2;
    const int ci_b = (ks & 3) * 16 + (lane >> 4) * 4;
    const int co = ct * 16 + (lane & 15);
    const float scale = (co < 64) ? QSCALE : 1.f;

    half4_t v;
    #pragma unroll
    for (int j = 0; j < 4; ++j)
        v[j] = (_Float16)(w[((size_t)co * 64 + ci_b + j) * 9 + tap] * scale);
    *reinterpret_cast<half4_t*>(&wf[(size_t)f * 4]) = v;
}

// ---------------------------------------------------------------------------
// Kernel 1: implicit-GEMM 3x3 conv via MFMA, staging fused (reads x f32
// directly; prep_xt kernel eliminated).
// Thread (ci = tid&63, ry = tid>>6) reads one 32-float row (8x dwordx4),
// converts, scalar-writes 34 halfs into chunk-XOR-swizzled LDS. Per write
// step a wave covers a bijective permutation of one 128B span -> 2 lanes
// per bank = conflict-free.
// ---------------------------------------------------------------------------
__global__ __launch_bounds__(256) void conv_mfma_kernel(
    const float* __restrict__ x1, const float* __restrict__ x2,
    const float* __restrict__ x12, const _Float16* __restrict__ wf,
    const float* __restrict__ b1, const float* __restrict__ b2,
    const float* __restrict__ b12, _Float16* __restrict__ qkv)
{
    __shared__ _Float16 xs[8704];        // 4*34*64
    const int strip = blockIdx.x;
    const int b = blockIdx.y, s = blockIdx.z;
    const int sb = s * Bn + b;
    const int tid = threadIdx.x;
    const int w = tid >> 6, lane = tid & 63, g = lane >> 4, lq = lane & 15;
    const int y0 = strip * 2;

    // ---- stage strip window directly from x (f32) into swizzled LDS -------
    {
        const float* xsrc = (s == 0) ? x1 : (s == 1) ? x2 : x12;
        const float* xb = xsrc + (size_t)b * CIN * HW;
        const int ci = tid & 63;
        const int ry = tid >> 6;             // 0..3
        const int gy = y0 - 1 + ry;
        f32x4 rowv[8];
        if ((unsigned)gy < 32u) {
            const f32x4* rp = reinterpret_cast<const f32x4*>(
                &xb[(size_t)ci * HW + gy * 32]);
            #pragma unroll
            for (int u = 0; u < 8; ++u) rowv[u] = rp[u];
        } else {
            #pragma unroll
            for (int u = 0; u < 8; ++u) rowv[u] = (f32x4){0.f, 0.f, 0.f, 0.f};
        }
        const int cchunk = ci >> 2, cbase = ci & 3;
        #pragma unroll
        for (int xx = 0; xx < 34; ++xx) {
            const int gx = xx - 1;
            float v = 0.f;
            if ((unsigned)gx < 32u) v = rowv[gx >> 2][gx & 3];
            xs[(ry * 34 + xx) * 64 + (((cchunk ^ (xx & 15)) << 2) + cbase)] =
                (_Float16)v;
        }
    }
    __syncthreads();

    f32x4 acc[3][4];
    #pragma unroll
    for (int cc = 0; cc < 3; ++cc)
        #pragma unroll
        for (int t = 0; t < 4; ++t) acc[cc][t] = (f32x4){0.f, 0.f, 0.f, 0.f};

    const _Float16* wfs = wf + ((size_t)(s * 12 + w * 3) * 36) * 256;

    #pragma unroll
    for (int tap = 0; tap < 9; ++tap) {
        const int ky = tap / 3, kx = tap % 3;
        #pragma unroll
        for (int sub = 0; sub < 4; ++sub) {
            const int ks = tap * 4 + sub;
            half4_t af[3];
            #pragma unroll
            for (int cc = 0; cc < 3; ++cc)
                af[cc] = *reinterpret_cast<const half4_t*>(
                    &wfs[((size_t)cc * 36 + ks) * 256 + lane * 4]);
            half4_t bf[4];
            #pragma unroll
            for (int t = 0; t < 4; ++t) {
                const int ry = (t >> 1) + ky;
                const int xx = (t & 1) * 16 + lq + kx;
                const int cichunk = sub * 4 + g;
                bf[t] = *reinterpret_cast<const half4_t*>(
                    &xs[(ry * 34 + xx) * 64 + ((cichunk ^ (xx & 15)) << 2)]);
            }
            #pragma unroll
            for (int cc = 0; cc < 3; ++cc)
                #pragma unroll
                for (int t = 0; t < 4; ++t)
                    acc[cc][t] = __builtin_amdgcn_mfma_f32_16x16x16f16(
                        af[cc], bf[t], acc[cc][t], 0, 0, 0);
        }
    }

    const float* bi = (s == 0) ? b1 : (s == 1) ? b2 : b12;
    _Float16* outb = qkv + (size_t)sb * CQKV * HW;
    #pragma unroll
    for (int cc = 0; cc < 3; ++cc) {
        const int ct = w * 3 + cc;
        const float bsc = (ct < 4) ? QSCALE : 1.f;
        const f32x4 bv4 = *reinterpret_cast<const f32x4*>(&bi[ct * 16 + g * 4]);
        #pragma unroll
        for (int t = 0; t < 4; ++t) {
            const int px = strip * 64 + t * 16 + lq;
            #pragma unroll
            for (int r = 0; r < 4; ++r) {
                const int ch = ct * 16 + g * 4 + r;
                outb[(size_t)ch * HW + px] = (_Float16)(acc[cc][t][r] + bsc * bv4[r]);
            }
        }
    }
}

// ---------------------------------------------------------------------------
// Kernel 2: rel-logit precompute, pre-shifted per query.
// ---------------------------------------------------------------------------
__global__ __launch_bounds__(256) void qrel_kernel(
    const _Float16* __restrict__ qkv,
    const float* __restrict__ relw, const float* __restrict__ relh,
    _Float16* __restrict__ qrel_t)
{
    __shared__ float rw_s[63 * 16], rh_s[63 * 16];
    const int bh = blockIdx.y;
    const int b  = bh >> 2, h = bh & 3;
    const int i  = blockIdx.x * 256 + threadIdx.x;

    for (int e = threadIdx.x; e < 1008; e += 256) {
        rw_s[e] = relw[e];
        rh_s[e] = relh[e];
    }
    __syncthreads();

    const _Float16* qb = qkv + ((size_t)b * CQKV + h * 16) * HW + i;
    f32x4 qv[4];
    #pragma unroll
    for (int d = 0; d < 16; ++d) qv[d >> 2][d & 3] = (float)qb[(size_t)d * HW];

    const int x1 = i & 31, y1 = i >> 5;
    _Float16 row[64];
    #pragma unroll
    for (int c = 0; c < 32; ++c) {
        const f32x4* wp = reinterpret_cast<const f32x4*>(&rw_s[(c + 31 - x1) * 16]);
        const f32x4* hp = reinterpret_cast<const f32x4*>(&rh_s[(c + 31 - y1) * 16]);
        float sw = 0.f, sh = 0.f;
        #pragma unroll
        for (int dq = 0; dq < 4; ++dq) {
            const f32x4 wv = wp[dq], hv = hp[dq], qq = qv[dq];
            #pragma unroll
            for (int e = 0; e < 4; ++e) {
                sw = fmaf(qq[e], wv[e], sw);
                sh = fmaf(qq[e], hv[e], sh);
            }
        }
        row[c]      = (_Float16)sw;
        row[32 + c] = (_Float16)sh;
    }

    _Float16* dst = qrel_t + ((size_t)bh * HW + i) * 64;
    #pragma unroll
    for (int u = 0; u < 8; ++u)
        *reinterpret_cast<half8_t*>(&dst[u * 8]) =
            *reinterpret_cast<const half8_t*>(&row[u * 8]);
}

// ---------------------------------------------------------------------------
// Kernel 3: MFMA flash attention (exp2 domain; rel-w as MFMA C-operand;
// rel-h folded into the subtracted max; pkrtz P packing).
// o16 written f16 in the r7-verified FLAT layout [sb][hd][i*16+dv]: the
// reference's raw (HW,DVH)->(DVH,H,W) reshape means conv channel c at px is
// flat element c*1024+px of this buffer (faithful garble) — do NOT "fix" it.
// ---------------------------------------------------------------------------
__global__ __launch_bounds__(512, 4) void attn_mfma_kernel(
    const _Float16* __restrict__ qkv,
    const _Float16* __restrict__ qrel_t,
    _Float16* __restrict__ o16)
{
    __shared__ _Float16 kf_lds[16384];   // 32 KB: K fragments
    __shared__ _Float16 vf_lds[16384];   // 32 KB: V fragments

    const int bid = blockIdx.x;
    const int S    = bid % 3;
    const int rest = bid / 3;
    const int bh   = rest & 31;
    const int qb   = rest >> 5;
    const int b   = bh >> 2, hd = bh & 3;
    const int tid = threadIdx.x;
    const int w    = tid >> 6;           // wave 0..7
    const int lane = tid & 63;
    const int g    = lane >> 4;
    const int lq   = lane & 15;
    const size_t SS = (size_t)Bn * CQKV * HW;

    const _Float16* qsrc = qkv + S * SS + ((size_t)b * CQKV + hd * 16) * HW;
    const _Float16* vsrc = qkv + S * SS + ((size_t)b * CQKV + 128 + hd * 16) * HW;
    const _Float16* k1p;
    const _Float16* k2p;
    if (S == 2) {
        k1p = qkv + 0 * SS + ((size_t)b * CQKV + 64 + hd * 16) * HW;
        k2p = qkv + 1 * SS + ((size_t)b * CQKV + 64 + hd * 16) * HW;
    } else {
        k1p = qkv + 2 * SS + ((size_t)b * CQKV + 64 + hd * 16) * HW;
        k2p = k1p;
    }

    // ---- stage K,V fragments (f16 global -> f16 LDS) ----------------------
    #pragma unroll 4
    for (int it = 0; it < 8; ++it) {
        const int idx = it * 512 + tid;          // 0..4095
        const int kt  = idx >> 6, l = idx & 63;
        const int row = l & 15;
        const int d0  = (l >> 4) * 4;
        const int lofs = (kt >> 1) * 512 + l * 8 + (kt & 1) * 4;

        const int key = kt * 16 + row;
        half4_t kh;
        if (S == 2) {
            #pragma unroll
            for (int j = 0; j < 4; ++j)
                kh[j] = (_Float16)((float)k1p[(size_t)(d0 + j) * HW + key]
                                 - (float)k2p[(size_t)(d0 + j) * HW + key]);
        } else {
            #pragma unroll
            for (int j = 0; j < 4; ++j)
                kh[j] = k1p[(size_t)(d0 + j) * HW + key];
        }
        *reinterpret_cast<half4_t*>(&kf_lds[lofs]) = kh;

        *reinterpret_cast<half4_t*>(&vf_lds[lofs]) =
            *reinterpret_cast<const half4_t*>(&vsrc[(size_t)row * HW + kt * 16 + d0]);
    }

    // ---- per-lane Q fragment + preloaded pre-shifted rel rows -------------
    const int qb0 = qb * 128 + w * 16;
    const int i   = qb0 + lq;

    half4_t qf;
    #pragma unroll
    for (int j = 0; j < 4; ++j) qf[j] = qsrc[(size_t)(g * 4 + j) * HW + i];

    f32x4 crw0 = {0.f, 0.f, 0.f, 0.f}, crw1 = {0.f, 0.f, 0.f, 0.f};
    half8_t qhr[4];
    if (S == 0) {
        const _Float16* rrow = qrel_t + ((size_t)bh * HW + i) * 64;
        const half4_t rw0 = *reinterpret_cast<const half4_t*>(&rrow[g * 4]);
        const half4_t rw1 = *reinterpret_cast<const half4_t*>(&rrow[16 + g * 4]);
        #pragma unroll
        for (int r = 0; r < 4; ++r) {
            crw0[r] = (float)rw0[r];
            crw1[r] = (float)rw1[r];
        }
        #pragma unroll
        for (int u = 0; u < 4; ++u)
            qhr[u] = *reinterpret_cast<const half8_t*>(&rrow[32 + u * 8]);
    } else {
        #pragma unroll
        for (int u = 0; u < 4; ++u)
            qhr[u] = (half8_t)(_Float16)0.f;
    }

    __syncthreads();

    f32x4 acc  = {0.f, 0.f, 0.f, 0.f};
    f32x4 accS = {0.f, 0.f, 0.f, 0.f};
    float m = -1e30f;
    const half4_t onef = {(_Float16)1.f, (_Float16)1.f, (_Float16)1.f, (_Float16)1.f};

    // ---- online-softmax sweep: fully unrolled 16 iters x 64 keys ----------
    #pragma unroll
    for (int c = 0; c < 32; c += 2) {
        const half8_t kk0 = *reinterpret_cast<const half8_t*>(&kf_lds[c * 512 + lane * 8]);
        const half8_t kk1 = *reinterpret_cast<const half8_t*>(&kf_lds[(c + 1) * 512 + lane * 8]);
        const half8_t vv0 = *reinterpret_cast<const half8_t*>(&vf_lds[c * 512 + lane * 8]);
        const half8_t vv1 = *reinterpret_cast<const half8_t*>(&vf_lds[(c + 1) * 512 + lane * 8]);

        const float rh0 = (float)qhr[c >> 3][c & 7];
        const float rh1 = (float)qhr[(c + 1) >> 3][(c + 1) & 7];

        // rel-w rides in on the C-operand (free add on the matrix pipe)
        f32x4 s0 = __builtin_amdgcn_mfma_f32_16x16x16f16(
            __builtin_shufflevector(kk0, kk0, 0, 1, 2, 3), qf, crw0, 0, 0, 0);
        f32x4 s1 = __builtin_amdgcn_mfma_f32_16x16x16f16(
            __builtin_shufflevector(kk0, kk0, 4, 5, 6, 7), qf, crw1, 0, 0, 0);
        f32x4 s2 = __builtin_amdgcn_mfma_f32_16x16x16f16(
            __builtin_shufflevector(kk1, kk1, 0, 1, 2, 3), qf, crw0, 0, 0, 0);
        f32x4 s3 = __builtin_amdgcn_mfma_f32_16x16x16f16(
            __builtin_shufflevector(kk1, kk1, 4, 5, 6, 7), qf, crw1, 0, 0, 0);

        float a0 = fmaxf(fmaxf(s0[0], s0[1]), fmaxf(s0[2], s0[3]));
        float a1 = fmaxf(fmaxf(s1[0], s1[1]), fmaxf(s1[2], s1[3]));
        float a2 = fmaxf(fmaxf(s2[0], s2[1]), fmaxf(s2[2], s2[3]));
        float a3 = fmaxf(fmaxf(s3[0], s3[1]), fmaxf(s3[2], s3[3]));
        // true score = s + rh  (rh uniform across the rows of each key-row)
        const float vmax = fmaxf(fmaxf(a0, a1) + rh0, fmaxf(a2, a3) + rh1);

        // defer-max: threshold 8 nats = 11.53 bits
        if (!__all(vmax <= m + 11.53f)) {
            float wmax = fmaxf(vmax, __shfl_xor(vmax, 16));
            wmax = fmaxf(wmax, __shfl_xor(wmax, 32));
            const float mnew = fmaxf(m, wmax);
            const float fsc  = EXP2F(m - mnew);
            m = mnew;
            acc  *= fsc;
            accS *= fsc;
        }

        // rel-h folds into the subtracted max
        const float mm0 = m - rh0;
        const float mm1 = m - rh1;

        const half4_t pa = pack4(EXP2F(s0[0] - mm0), EXP2F(s0[1] - mm0),
                                 EXP2F(s0[2] - mm0), EXP2F(s0[3] - mm0));
        const half4_t pb = pack4(EXP2F(s1[0] - mm0), EXP2F(s1[1] - mm0),
                                 EXP2F(s1[2] - mm0), EXP2F(s1[3] - mm0));
        const half4_t pc = pack4(EXP2F(s2[0] - mm1), EXP2F(s2[1] - mm1),
                                 EXP2F(s2[2] - mm1), EXP2F(s2[3] - mm1));
        const half4_t pd = pack4(EXP2F(s3[0] - mm1), EXP2F(s3[1] - mm1),
                                 EXP2F(s3[2] - mm1), EXP2F(s3[3] - mm1));

        acc = __builtin_amdgcn_mfma_f32_16x16x16f16(
            __builtin_shufflevector(vv0, vv0, 0, 1, 2, 3), pa, acc, 0, 0, 0);
        acc = __builtin_amdgcn_mfma_f32_16x16x16f16(
            __builtin_shufflevector(vv0, vv0, 4, 5, 6, 7), pb, acc, 0, 0, 0);
        acc = __builtin_amdgcn_mfma_f32_16x16x16f16(
            __builtin_shufflevector(vv1, vv1, 0, 1, 2, 3), pc, acc, 0, 0, 0);
        acc = __builtin_amdgcn_mfma_f32_16x16x16f16(
            __builtin_shufflevector(vv1, vv1, 4, 5, 6, 7), pd, acc, 0, 0, 0);

        accS = __builtin_amdgcn_mfma_f32_16x16x16f16(onef, pa, accS, 0, 0, 0);
        accS = __builtin_amdgcn_mfma_f32_16x16x16f16(onef, pb, accS, 0, 0, 0);
        accS = __builtin_amdgcn_mfma_f32_16x16x16f16(onef, pc, accS, 0, 0, 0);
        accS = __builtin_amdgcn_mfma_f32_16x16x16f16(onef, pd, accS, 0, 0, 0);
    }

    const float inv = 1.f / accS[0];

    // FLAT r7 layout: o16[sb][hd][i*16 + dv], dv = g*4 + r  (contiguous half4)
    _Float16* op = o16 + (size_t)(S * Bn + b) * 65536 + (size_t)hd * 16384
                 + (size_t)i * 16 + g * 4;
    *reinterpret_cast<half4_t*>(op) =
        pack4(acc[0] * inv, acc[1] * inv, acc[2] * inv, acc[3] * inv);
}

// ---------------------------------------------------------------------------
// Kernel 4: 1x1 output conv via MFMA, faithful to the reference's raw reshape:
// conv input channel c at pixel px = o16[sb*65536 + c*1024 + px]  (V[c][px]).
// Stage V-strip TRANSPOSED into LDS ([t][c], chunk-XOR swizzled) so B-frags
// are contiguous conflict-free half4 reads. A-side (wout) as before.
// grid (16 px-strips, 24 sb), block 256 = 4 waves; wave w -> co-tile w.
// ---------------------------------------------------------------------------
__global__ __launch_bounds__(256) void out_conv_mfma_kernel(
    const _Float16* __restrict__ o16, const float* __restrict__ wout,
    const float* __restrict__ bout, float* __restrict__ out)
{
    __shared__ _Float16 wls[4096];   // w[co][ci], chunk c>>2 stored at ^co&15
    __shared__ _Float16 ols[4096];   // V^T[t][c], chunk c>>2 stored at ^t&15
    const int strip = blockIdx.x;
    const int sb    = blockIdx.y;
    const int tid = threadIdx.x;
    const int w = tid >> 6, lane = tid & 63, g = lane >> 4, lq = lane & 15;

    // ---- stage wout (f32->f16, swizzled) -----------------------------------
    {
        const int row = tid >> 2;            // co 0..63
        const int cg  = (tid & 3) * 4;       // chunk group base
        #pragma unroll
        for (int k = 0; k < 4; ++k) {
            const int c = cg + k;            // chunk 0..15 (4 halfs each)
            const f32x4 wv = *reinterpret_cast<const f32x4*>(&wout[(row * 16 + c) * 4]);
            *reinterpret_cast<half4_t*>(&wls[row * 64 + ((c ^ (row & 15)) << 2)]) =
                pack4(wv[0], wv[1], wv[2], wv[3]);
        }
    }
    // ---- stage V-strip transposed: ols[t][c] = V[c][strip*64 + t] ----------
    {
        const _Float16* osrc = o16 + (size_t)sb * 65536 + strip * 64;
        #pragma unroll
        for (int it = 0; it < 2; ++it) {
            const int idx = it * 256 + tid;      // 0..511
            const int c   = idx >> 3;            // channel 0..63
            const int t0  = (idx & 7) * 8;       // px-local base
            const half8_t v = *reinterpret_cast<const half8_t*>(
                &osrc[(size_t)c * HW + t0]);
            #pragma unroll
            for (int e = 0; e < 8; ++e) {
                const int t = t0 + e;
                ols[t * 64 + ((((c >> 2) ^ (t & 15)) << 2) + (c & 3))] = v[e];
            }
        }
    }
    __syncthreads();

    // ---- A fragments: w[co = w*16+lq][ci = ks*16 + g*4 + j] ----------------
    half4_t af[4];
    #pragma unroll
    for (int ks = 0; ks < 4; ++ks)
        af[ks] = *reinterpret_cast<const half4_t*>(
            &wls[(w * 16 + lq) * 64 + (((ks * 4 + g) ^ lq) << 2)]);

    const f32x4 bv4 = *reinterpret_cast<const f32x4*>(&bout[w * 16 + g * 4]);

    #pragma unroll
    for (int pt = 0; pt < 4; ++pt) {
        f32x4 acc = {0.f, 0.f, 0.f, 0.f};
        #pragma unroll
        for (int ks = 0; ks < 4; ++ks) {
            // B[k = ci-local][n = t]: ols[t][ci = ks*16 + g*4 + j]
            const half4_t bf = *reinterpret_cast<const half4_t*>(
                &ols[(pt * 16 + lq) * 64 + (((ks * 4 + g) ^ lq) << 2)]);
            acc = __builtin_amdgcn_mfma_f32_16x16x16f16(af[ks], bf, acc, 0, 0, 0);
        }
        const int px = strip * 64 + pt * 16 + lq;
        #pragma unroll
        for (int r = 0; r < 4; ++r) {
            const int co = w * 16 + g * 4 + r;
            out[((size_t)sb * 64 + co) * HW + px] = acc[r] + bv4[r];
        }
    }
}

// ---------------------------------------------------------------------------
extern "C" void kernel_launch(void* const* d_in, const int* in_sizes, int n_in,
                              void* d_out, int out_size, void* d_ws, size_t ws_size,
                              hipStream_t stream)
{
    const float* x1   = (const float*)d_in[0];
    const float* x2   = (const float*)d_in[1];
    const float* x12  = (const float*)d_in[2];
    const float* wq1  = (const float*)d_in[3];
    const float* bq1  = (const float*)d_in[4];
    const float* wq2  = (const float*)d_in[5];
    const float* bq2  = (const float*)d_in[6];
    const float* wq12 = (const float*)d_in[7];
    const float* bq12 = (const float*)d_in[8];
    const float* wout = (const float*)d_in[9];
    const float* bout = (const float*)d_in[10];
    const float* relw = (const float*)d_in[11];
    const float* relh = (const float*)d_in[12];

    // workspace: qkv16 | o16 | qrel_t | wf  (all f16, ~17 MB)
    _Float16* qkv16  = (_Float16*)d_ws;                       // 4,718,592 h
    _Float16* o16    = qkv16 + (size_t)4718592;               // 1,572,864 h
    _Float16* qrel_t = o16 + (size_t)1572864;                 // 2,097,152 h
    _Float16* wf     = qrel_t + (size_t)2097152;              //   331,776 h

    prep_wf_kernel<<<dim3(324), 256, 0, stream>>>(wq1, wq2, wq12, wf);

    conv_mfma_kernel<<<dim3(16, 8, 3), 256, 0, stream>>>(
        x1, x2, x12, wf, bq1, bq2, bq12, qkv16);

    qrel_kernel<<<dim3(4, 32), 256, 0, stream>>>(qkv16, relw, relh, qrel_t);

    attn_mfma_kernel<<<dim3(768), 512, 0, stream>>>(qkv16, qrel_t, o16);

    out_conv_mfma_kernel<<<dim3(16, 24), 256, 0, stream>>>(
        o16, wout, bout, (float*)d_out);
}

// Round 13
// 71.872 us; speedup vs baseline: 3.1303x; 1.0105x over previous
//
#include <hip/hip_runtime.h>
#include <math.h>

#define Bn 8
#define CIN 64
#define HH 32
#define WW 32
#define HW 1024
#define CQKV 192
#define NHh 4
#define DKHd 16
#define DVHd 16
#define QSCALE 0.36067376f   // 0.25 * log2(e): whole softmax lives in exp2 domain

typedef _Float16 half4_t __attribute__((ext_vector_type(4)));
typedef _Float16 half8_t __attribute__((ext_vector_type(8)));
typedef __fp16 fp16x2_t __attribute__((ext_vector_type(2)));
typedef __fp16 fp16x4_t __attribute__((ext_vector_type(4)));
typedef float f32x4 __attribute__((ext_vector_type(4)));

#if __has_builtin(__builtin_amdgcn_exp2f)
#define EXP2F(x) __builtin_amdgcn_exp2f(x)
#else
#define EXP2F(x) exp2f(x)
#endif

static __device__ __forceinline__ half4_t pack4(float a, float b, float c, float d)
{
#if __has_builtin(__builtin_amdgcn_cvt_pkrtz)
    fp16x2_t lo = __builtin_amdgcn_cvt_pkrtz(a, b);
    fp16x2_t hi = __builtin_amdgcn_cvt_pkrtz(c, d);
    fp16x4_t v4 = __builtin_shufflevector(lo, hi, 0, 1, 2, 3);
    return __builtin_bit_cast(half4_t, v4);
#else
    half4_t r;
    r[0] = (_Float16)a; r[1] = (_Float16)b; r[2] = (_Float16)c; r[3] = (_Float16)d;
    return r;
#endif
}

// ---------------------------------------------------------------------------
// Prep B: weights -> A-fragment layout wf[s][ct(12)][ks(36)][lane(64)][4] f16.
// ---------------------------------------------------------------------------
__global__ __launch_bounds__(256) void prep_wf_kernel(
    const float* __restrict__ w1, const float* __restrict__ w2,
    const float* __restrict__ w12, _Float16* __restrict__ wf)
{
    const int f = blockIdx.x * 256 + threadIdx.x;   // 82944 frags
    if (f >= 3 * 12 * 36 * 64) return;
    const int lane = f & 63;
    int r = f >> 6;
    const int ks = r % 36; r /= 36;
    const int ct = r % 12; const int s = r / 12;
    const float* w = (s == 0) ? w1 : (s == 1) ? w2 : w12;

    const int tap = ks >> 2;
    const int ci_b = (ks & 3) * 16 + (lane >> 4) * 4;
    const int co = ct * 16 + (lane & 15);
    const float scale = (co < 64) ? QSCALE : 1.f;

    half4_t v;
    #pragma unroll
    for (int j = 0; j < 4; ++j)
        v[j] = (_Float16)(w[((size_t)co * 64 + ci_b + j) * 9 + tap] * scale);
    *reinterpret_cast<half4_t*>(&wf[(size_t)f * 4]) = v;
}

// ---------------------------------------------------------------------------
// Kernel 1: implicit-GEMM 3x3 conv via MFMA, staging fused (reads x f32).
// ---------------------------------------------------------------------------
__global__ __launch_bounds__(256) void conv_mfma_kernel(
    const float* __restrict__ x1, const float* __restrict__ x2,
    const float* __restrict__ x12, const _Float16* __restrict__ wf,
    const float* __restrict__ b1, const float* __restrict__ b2,
    const float* __restrict__ b12, _Float16* __restrict__ qkv)
{
    __shared__ _Float16 xs[8704];        // 4*34*64
    const int strip = blockIdx.x;
    const int b = blockIdx.y, s = blockIdx.z;
    const int sb = s * Bn + b;
    const int tid = threadIdx.x;
    const int w = tid >> 6, lane = tid & 63, g = lane >> 4, lq = lane & 15;
    const int y0 = strip * 2;

    // ---- stage strip window directly from x (f32) into swizzled LDS -------
    {
        const float* xsrc = (s == 0) ? x1 : (s == 1) ? x2 : x12;
        const float* xb = xsrc + (size_t)b * CIN * HW;
        const int ci = tid & 63;
        const int ry = tid >> 6;             // 0..3
        const int gy = y0 - 1 + ry;
        f32x4 rowv[8];
        if ((unsigned)gy < 32u) {
            const f32x4* rp = reinterpret_cast<const f32x4*>(
                &xb[(size_t)ci * HW + gy * 32]);
            #pragma unroll
            for (int u = 0; u < 8; ++u) rowv[u] = rp[u];
        } else {
            #pragma unroll
            for (int u = 0; u < 8; ++u) rowv[u] = (f32x4){0.f, 0.f, 0.f, 0.f};
        }
        const int cchunk = ci >> 2, cbase = ci & 3;
        #pragma unroll
        for (int xx = 0; xx < 34; ++xx) {
            const int gx = xx - 1;
            float v = 0.f;
            if ((unsigned)gx < 32u) v = rowv[gx >> 2][gx & 3];
            xs[(ry * 34 + xx) * 64 + (((cchunk ^ (xx & 15)) << 2) + cbase)] =
                (_Float16)v;
        }
    }
    __syncthreads();

    f32x4 acc[3][4];
    #pragma unroll
    for (int cc = 0; cc < 3; ++cc)
        #pragma unroll
        for (int t = 0; t < 4; ++t) acc[cc][t] = (f32x4){0.f, 0.f, 0.f, 0.f};

    const _Float16* wfs = wf + ((size_t)(s * 12 + w * 3) * 36) * 256;

    #pragma unroll
    for (int tap = 0; tap < 9; ++tap) {
        const int ky = tap / 3, kx = tap % 3;
        #pragma unroll
        for (int sub = 0; sub < 4; ++sub) {
            const int ks = tap * 4 + sub;
            half4_t af[3];
            #pragma unroll
            for (int cc = 0; cc < 3; ++cc)
                af[cc] = *reinterpret_cast<const half4_t*>(
                    &wfs[((size_t)cc * 36 + ks) * 256 + lane * 4]);
            half4_t bf[4];
            #pragma unroll
            for (int t = 0; t < 4; ++t) {
                const int ry = (t >> 1) + ky;
                const int xx = (t & 1) * 16 + lq + kx;
                const int cichunk = sub * 4 + g;
                bf[t] = *reinterpret_cast<const half4_t*>(
                    &xs[(ry * 34 + xx) * 64 + ((cichunk ^ (xx & 15)) << 2)]);
            }
            #pragma unroll
            for (int cc = 0; cc < 3; ++cc)
                #pragma unroll
                for (int t = 0; t < 4; ++t)
                    acc[cc][t] = __builtin_amdgcn_mfma_f32_16x16x16f16(
                        af[cc], bf[t], acc[cc][t], 0, 0, 0);
        }
    }

    const float* bi = (s == 0) ? b1 : (s == 1) ? b2 : b12;
    _Float16* outb = qkv + (size_t)sb * CQKV * HW;
    #pragma unroll
    for (int cc = 0; cc < 3; ++cc) {
        const int ct = w * 3 + cc;
        const float bsc = (ct < 4) ? QSCALE : 1.f;
        const f32x4 bv4 = *reinterpret_cast<const f32x4*>(&bi[ct * 16 + g * 4]);
        #pragma unroll
        for (int t = 0; t < 4; ++t) {
            const int px = strip * 64 + t * 16 + lq;
            #pragma unroll
            for (int r = 0; r < 4; ++r) {
                const int ch = ct * 16 + g * 4 + r;
                outb[(size_t)ch * HW + px] = (_Float16)(acc[cc][t][r] + bsc * bv4[r]);
            }
        }
    }
}

// ---------------------------------------------------------------------------
// Kernel 2: rel-logit precompute, pre-shifted per query (unchanged).
// ---------------------------------------------------------------------------
__global__ __launch_bounds__(256) void qrel_kernel(
    const _Float16* __restrict__ qkv,
    const float* __restrict__ relw, const float* __restrict__ relh,
    _Float16* __restrict__ qrel_t)
{
    __shared__ float rw_s[63 * 16], rh_s[63 * 16];
    const int bh = blockIdx.y;
    const int b  = bh >> 2, h = bh & 3;
    const int i  = blockIdx.x * 256 + threadIdx.x;

    for (int e = threadIdx.x; e < 1008; e += 256) {
        rw_s[e] = relw[e];
        rh_s[e] = relh[e];
    }
    __syncthreads();

    const _Float16* qb = qkv + ((size_t)b * CQKV + h * 16) * HW + i;
    f32x4 qv[4];
    #pragma unroll
    for (int d = 0; d < 16; ++d) qv[d >> 2][d & 3] = (float)qb[(size_t)d * HW];

    const int x1 = i & 31, y1 = i >> 5;
    _Float16 row[64];
    #pragma unroll
    for (int c = 0; c < 32; ++c) {
        const f32x4* wp = reinterpret_cast<const f32x4*>(&rw_s[(c + 31 - x1) * 16]);
        const f32x4* hp = reinterpret_cast<const f32x4*>(&rh_s[(c + 31 - y1) * 16]);
        float sw = 0.f, sh = 0.f;
        #pragma unroll
        for (int dq = 0; dq < 4; ++dq) {
            const f32x4 wv = wp[dq], hv = hp[dq], qq = qv[dq];
            #pragma unroll
            for (int e = 0; e < 4; ++e) {
                sw = fmaf(qq[e], wv[e], sw);
                sh = fmaf(qq[e], hv[e], sh);
            }
        }
        row[c]      = (_Float16)sw;
        row[32 + c] = (_Float16)sh;
    }

    _Float16* dst = qrel_t + ((size_t)bh * HW + i) * 64;
    #pragma unroll
    for (int u = 0; u < 8; ++u)
        *reinterpret_cast<half8_t*>(&dst[u * 8]) =
            *reinterpret_cast<const half8_t*>(&row[u * 8]);
}

// ---------------------------------------------------------------------------
// Kernel 3: MFMA flash attention, SPLIT-K x2.
// grid 1536: kh = bid&1 selects keys [kh*512, kh*512+512); each block stages
// 16+16 KB LDS -> 4 blocks/CU x 8 waves = 32 waves/CU (2x round-11 occupancy).
// Writes unnormalized partials: pacc (f32x4/lane) + pms (m, sumP per query).
// Combine kernel merges halves with the standard flash merge.
// ---------------------------------------------------------------------------
__global__ __launch_bounds__(512, 8) void attn_mfma_kernel(
    const _Float16* __restrict__ qkv,
    const _Float16* __restrict__ qrel_t,
    float* __restrict__ pacc, float2* __restrict__ pms)
{
    __shared__ _Float16 kf_lds[8192];   // 16 KB: K fragments (512 keys)
    __shared__ _Float16 vf_lds[8192];   // 16 KB: V fragments

    const int bid = blockIdx.x;
    const int kh   = bid & 1;            // key half
    const int r2   = bid >> 1;
    const int S    = r2 % 3;
    const int r3   = r2 / 3;
    const int bh   = r3 & 31;
    const int qb   = r3 >> 5;
    const int b   = bh >> 2, hd = bh & 3;
    const int tid = threadIdx.x;
    const int w    = tid >> 6;           // wave 0..7
    const int lane = tid & 63;
    const int g    = lane >> 4;
    const int lq   = lane & 15;
    const size_t SS = (size_t)Bn * CQKV * HW;

    const _Float16* qsrc = qkv + S * SS + ((size_t)b * CQKV + hd * 16) * HW;
    const _Float16* vsrc = qkv + S * SS + ((size_t)b * CQKV + 128 + hd * 16) * HW;
    const _Float16* k1p;
    const _Float16* k2p;
    if (S == 2) {
        k1p = qkv + 0 * SS + ((size_t)b * CQKV + 64 + hd * 16) * HW;
        k2p = qkv + 1 * SS + ((size_t)b * CQKV + 64 + hd * 16) * HW;
    } else {
        k1p = qkv + 2 * SS + ((size_t)b * CQKV + 64 + hd * 16) * HW;
        k2p = k1p;
    }

    // ---- stage this half's K,V fragments (f16 global -> f16 LDS) ----------
    #pragma unroll 4
    for (int it = 0; it < 4; ++it) {
        const int idx = it * 512 + tid;          // 0..2047
        const int ktl = idx >> 6, l = idx & 63;  // ktl 0..31
        const int row = l & 15;
        const int d0  = (l >> 4) * 4;
        const int lofs = (ktl >> 1) * 512 + l * 8 + (ktl & 1) * 4;

        const int key = kh * 512 + ktl * 16 + row;
        half4_t kh4;
        if (S == 2) {
            #pragma unroll
            for (int j = 0; j < 4; ++j)
                kh4[j] = (_Float16)((float)k1p[(size_t)(d0 + j) * HW + key]
                                  - (float)k2p[(size_t)(d0 + j) * HW + key]);
        } else {
            #pragma unroll
            for (int j = 0; j < 4; ++j)
                kh4[j] = k1p[(size_t)(d0 + j) * HW + key];
        }
        *reinterpret_cast<half4_t*>(&kf_lds[lofs]) = kh4;

        *reinterpret_cast<half4_t*>(&vf_lds[lofs]) =
            *reinterpret_cast<const half4_t*>(&vsrc[(size_t)row * HW + kh * 512 + ktl * 16 + d0]);
    }

    // ---- per-lane Q fragment + preloaded pre-shifted rel rows -------------
    const int qb0 = qb * 128 + w * 16;
    const int i   = qb0 + lq;

    half4_t qf;
    #pragma unroll
    for (int j = 0; j < 4; ++j) qf[j] = qsrc[(size_t)(g * 4 + j) * HW + i];

    f32x4 crw0 = {0.f, 0.f, 0.f, 0.f}, crw1 = {0.f, 0.f, 0.f, 0.f};
    half8_t qhr[2];
    if (S == 0) {
        const _Float16* rrow = qrel_t + ((size_t)bh * HW + i) * 64;
        const half4_t rw0 = *reinterpret_cast<const half4_t*>(&rrow[g * 4]);
        const half4_t rw1 = *reinterpret_cast<const half4_t*>(&rrow[16 + g * 4]);
        #pragma unroll
        for (int r = 0; r < 4; ++r) {
            crw0[r] = (float)rw0[r];
            crw1[r] = (float)rw1[r];
        }
        qhr[0] = *reinterpret_cast<const half8_t*>(&rrow[32 + kh * 16]);
        qhr[1] = *reinterpret_cast<const half8_t*>(&rrow[40 + kh * 16]);
    } else {
        qhr[0] = (half8_t)(_Float16)0.f;
        qhr[1] = (half8_t)(_Float16)0.f;
    }

    __syncthreads();

    f32x4 acc  = {0.f, 0.f, 0.f, 0.f};
    f32x4 accS = {0.f, 0.f, 0.f, 0.f};
    float m = -1e30f;
    const half4_t onef = {(_Float16)1.f, (_Float16)1.f, (_Float16)1.f, (_Float16)1.f};

    // ---- online-softmax sweep: fully unrolled 8 iters x 64 keys -----------
    #pragma unroll
    for (int c = 0; c < 16; c += 2) {
        const half8_t kk0 = *reinterpret_cast<const half8_t*>(&kf_lds[c * 512 + lane * 8]);
        const half8_t kk1 = *reinterpret_cast<const half8_t*>(&kf_lds[(c + 1) * 512 + lane * 8]);
        const half8_t vv0 = *reinterpret_cast<const half8_t*>(&vf_lds[c * 512 + lane * 8]);
        const half8_t vv1 = *reinterpret_cast<const half8_t*>(&vf_lds[(c + 1) * 512 + lane * 8]);

        const float rh0 = (float)qhr[c >> 3][c & 7];
        const float rh1 = (float)qhr[(c + 1) >> 3][(c + 1) & 7];

        // rel-w rides in on the C-operand (free add on the matrix pipe)
        f32x4 s0 = __builtin_amdgcn_mfma_f32_16x16x16f16(
            __builtin_shufflevector(kk0, kk0, 0, 1, 2, 3), qf, crw0, 0, 0, 0);
        f32x4 s1 = __builtin_amdgcn_mfma_f32_16x16x16f16(
            __builtin_shufflevector(kk0, kk0, 4, 5, 6, 7), qf, crw1, 0, 0, 0);
        f32x4 s2 = __builtin_amdgcn_mfma_f32_16x16x16f16(
            __builtin_shufflevector(kk1, kk1, 0, 1, 2, 3), qf, crw0, 0, 0, 0);
        f32x4 s3 = __builtin_amdgcn_mfma_f32_16x16x16f16(
            __builtin_shufflevector(kk1, kk1, 4, 5, 6, 7), qf, crw1, 0, 0, 0);

        float a0 = fmaxf(fmaxf(s0[0], s0[1]), fmaxf(s0[2], s0[3]));
        float a1 = fmaxf(fmaxf(s1[0], s1[1]), fmaxf(s1[2], s1[3]));
        float a2 = fmaxf(fmaxf(s2[0], s2[1]), fmaxf(s2[2], s2[3]));
        float a3 = fmaxf(fmaxf(s3[0], s3[1]), fmaxf(s3[2], s3[3]));
        const float vmax = fmaxf(fmaxf(a0, a1) + rh0, fmaxf(a2, a3) + rh1);

        // defer-max: threshold 8 nats = 11.53 bits
        if (!__all(vmax <= m + 11.53f)) {
            float wmax = fmaxf(vmax, __shfl_xor(vmax, 16));
            wmax = fmaxf(wmax, __shfl_xor(wmax, 32));
            const float mnew = fmaxf(m, wmax);
            const float fsc  = EXP2F(m - mnew);
            m = mnew;
            acc  *= fsc;
            accS *= fsc;
        }

        const float mm0 = m - rh0;
        const float mm1 = m - rh1;

        const half4_t pa = pack4(EXP2F(s0[0] - mm0), EXP2F(s0[1] - mm0),
                                 EXP2F(s0[2] - mm0), EXP2F(s0[3] - mm0));
        const half4_t pb = pack4(EXP2F(s1[0] - mm0), EXP2F(s1[1] - mm0),
                                 EXP2F(s1[2] - mm0), EXP2F(s1[3] - mm0));
        const half4_t pc = pack4(EXP2F(s2[0] - mm1), EXP2F(s2[1] - mm1),
                                 EXP2F(s2[2] - mm1), EXP2F(s2[3] - mm1));
        const half4_t pd = pack4(EXP2F(s3[0] - mm1), EXP2F(s3[1] - mm1),
                                 EXP2F(s3[2] - mm1), EXP2F(s3[3] - mm1));

        acc = __builtin_amdgcn_mfma_f32_16x16x16f16(
            __builtin_shufflevector(vv0, vv0, 0, 1, 2, 3), pa, acc, 0, 0, 0);
        acc = __builtin_amdgcn_mfma_f32_16x16x16f16(
            __builtin_shufflevector(vv0, vv0, 4, 5, 6, 7), pb, acc, 0, 0, 0);
        acc = __builtin_amdgcn_mfma_f32_16x16x16f16(
            __builtin_shufflevector(vv1, vv1, 0, 1, 2, 3), pc, acc, 0, 0, 0);
        acc = __builtin_amdgcn_mfma_f32_16x16x16f16(
            __builtin_shufflevector(vv1, vv1, 4, 5, 6, 7), pd, acc, 0, 0, 0);

        accS = __builtin_amdgcn_mfma_f32_16x16x16f16(onef, pa, accS, 0, 0, 0);
        accS = __builtin_amdgcn_mfma_f32_16x16x16f16(onef, pb, accS, 0, 0, 0);
        accS = __builtin_amdgcn_mfma_f32_16x16x16f16(onef, pc, accS, 0, 0, 0);
        accS = __builtin_amdgcn_mfma_f32_16x16x16f16(onef, pd, accS, 0, 0, 0);
    }

    // ---- write unnormalized partials --------------------------------------
    const int qh = (S * Bn + b) * NHh + hd;          // 0..95
    float* pa = pacc + (size_t)kh * 1572864 + ((size_t)qh * 1024 + i) * 16 + g * 4;
    *reinterpret_cast<f32x4*>(pa) = acc;
    if (g == 0)
        pms[(size_t)kh * 98304 + (size_t)qh * 1024 + i] = make_float2(m, accS[0]);
}

// ---------------------------------------------------------------------------
// Kernel 3b: combine the two key-halves (flash merge), write o16 flat layout.
// ---------------------------------------------------------------------------
__global__ __launch_bounds__(256) void combine_kernel(
    const float* __restrict__ pacc, const float2* __restrict__ pms,
    _Float16* __restrict__ o16)
{
    const int idx = blockIdx.x * 256 + threadIdx.x;   // 0..393215
    const int g = idx & 3;
    const int q = idx >> 2;                            // qh*1024 + i

    const float2 ms0 = pms[q];
    const float2 ms1 = pms[98304 + q];
    const f32x4 a0 = *reinterpret_cast<const f32x4*>(&pacc[(size_t)q * 16 + g * 4]);
    const f32x4 a1 = *reinterpret_cast<const f32x4*>(&pacc[(size_t)1572864 + (size_t)q * 16 + g * 4]);

    const float M  = fmaxf(ms0.x, ms1.x);
    const float w0 = EXP2F(ms0.x - M);
    const float w1 = EXP2F(ms1.x - M);
    const float inv = 1.f / (w0 * ms0.y + w1 * ms1.y);

    *reinterpret_cast<half4_t*>(&o16[(size_t)q * 16 + g * 4]) =
        pack4((w0 * a0[0] + w1 * a1[0]) * inv, (w0 * a0[1] + w1 * a1[1]) * inv,
              (w0 * a0[2] + w1 * a1[2]) * inv, (w0 * a0[3] + w1 * a1[3]) * inv);
}

// ---------------------------------------------------------------------------
// Kernel 4: 1x1 output conv via MFMA (faithful raw-reshape view; unchanged).
// ---------------------------------------------------------------------------
__global__ __launch_bounds__(256) void out_conv_mfma_kernel(
    const _Float16* __restrict__ o16, const float* __restrict__ wout,
    const float* __restrict__ bout, float* __restrict__ out)
{
    __shared__ _Float16 wls[4096];   // w[co][ci], chunk c>>2 stored at ^co&15
    __shared__ _Float16 ols[4096];   // V^T[t][c], chunk c>>2 stored at ^t&15
    const int strip = blockIdx.x;
    const int sb    = blockIdx.y;
    const int tid = threadIdx.x;
    const int w = tid >> 6, lane = tid & 63, g = lane >> 4, lq = lane & 15;

    {
        const int row = tid >> 2;            // co 0..63
        const int cg  = (tid & 3) * 4;       // chunk group base
        #pragma unroll
        for (int k = 0; k < 4; ++k) {
            const int c = cg + k;
            const f32x4 wv = *reinterpret_cast<const f32x4*>(&wout[(row * 16 + c) * 4]);
            *reinterpret_cast<half4_t*>(&wls[row * 64 + ((c ^ (row & 15)) << 2)]) =
                pack4(wv[0], wv[1], wv[2], wv[3]);
        }
    }
    {
        const _Float16* osrc = o16 + (size_t)sb * 65536 + strip * 64;
        #pragma unroll
        for (int it = 0; it < 2; ++it) {
            const int idx = it * 256 + tid;      // 0..511
            const int c   = idx >> 3;            // channel 0..63
            const int t0  = (idx & 7) * 8;       // px-local base
            const half8_t v = *reinterpret_cast<const half8_t*>(
                &osrc[(size_t)c * HW + t0]);
            #pragma unroll
            for (int e = 0; e < 8; ++e) {
                const int t = t0 + e;
                ols[t * 64 + ((((c >> 2) ^ (t & 15)) << 2) + (c & 3))] = v[e];
            }
        }
    }
    __syncthreads();

    half4_t af[4];
    #pragma unroll
    for (int ks = 0; ks < 4; ++ks)
        af[ks] = *reinterpret_cast<const half4_t*>(
            &wls[(w * 16 + lq) * 64 + (((ks * 4 + g) ^ lq) << 2)]);

    const f32x4 bv4 = *reinterpret_cast<const f32x4*>(&bout[w * 16 + g * 4]);

    #pragma unroll
    for (int pt = 0; pt < 4; ++pt) {
        f32x4 acc = {0.f, 0.f, 0.f, 0.f};
        #pragma unroll
        for (int ks = 0; ks < 4; ++ks) {
            const half4_t bf = *reinterpret_cast<const half4_t*>(
                &ols[(pt * 16 + lq) * 64 + (((ks * 4 + g) ^ lq) << 2)]);
            acc = __builtin_amdgcn_mfma_f32_16x16x16f16(af[ks], bf, acc, 0, 0, 0);
        }
        const int px = strip * 64 + pt * 16 + lq;
        #pragma unroll
        for (int r = 0; r < 4; ++r) {
            const int co = w * 16 + g * 4 + r;
            out[((size_t)sb * 64 + co) * HW + px] = acc[r] + bv4[r];
        }
    }
}

// ---------------------------------------------------------------------------
extern "C" void kernel_launch(void* const* d_in, const int* in_sizes, int n_in,
                              void* d_out, int out_size, void* d_ws, size_t ws_size,
                              hipStream_t stream)
{
    const float* x1   = (const float*)d_in[0];
    const float* x2   = (const float*)d_in[1];
    const float* x12  = (const float*)d_in[2];
    const float* wq1  = (const float*)d_in[3];
    const float* bq1  = (const float*)d_in[4];
    const float* wq2  = (const float*)d_in[5];
    const float* bq2  = (const float*)d_in[6];
    const float* wq12 = (const float*)d_in[7];
    const float* bq12 = (const float*)d_in[8];
    const float* wout = (const float*)d_in[9];
    const float* bout = (const float*)d_in[10];
    const float* relw = (const float*)d_in[11];
    const float* relh = (const float*)d_in[12];

    // workspace: qkv16 | o16 | qrel_t | wf | pacc | pms  (~31.6 MB)
    _Float16* qkv16  = (_Float16*)d_ws;                       // 4,718,592 h
    _Float16* o16    = qkv16 + (size_t)4718592;               // 1,572,864 h
    _Float16* qrel_t = o16 + (size_t)1572864;                 // 2,097,152 h
    _Float16* wf     = qrel_t + (size_t)2097152;              //   331,776 h
    float*    pacc   = (float*)(wf + (size_t)331776);         // 3,145,728 f
    float2*   pms    = (float2*)(pacc + (size_t)3145728);     //   196,608 f2

    prep_wf_kernel<<<dim3(324), 256, 0, stream>>>(wq1, wq2, wq12, wf);

    conv_mfma_kernel<<<dim3(16, 8, 3), 256, 0, stream>>>(
        x1, x2, x12, wf, bq1, bq2, bq12, qkv16);

    qrel_kernel<<<dim3(4, 32), 256, 0, stream>>>(qkv16, relw, relh, qrel_t);

    attn_mfma_kernel<<<dim3(1536), 512, 0, stream>>>(qkv16, qrel_t, pacc, pms);

    combine_kernel<<<dim3(1536), 256, 0, stream>>>(pacc, pms, o16);

    out_conv_mfma_kernel<<<dim3(16, 24), 256, 0, stream>>>(
        o16, wout, bout, (float*)d_out);
}